// Round 15
// baseline (707.220 us; speedup 1.0000x reference)
//
#include <hip/hip_runtime.h>
#include <cstdint>
#include <cstddef>

#define IN_DIM 128
#define HID    512

typedef unsigned int   uint32;
typedef unsigned short u16;
typedef __attribute__((ext_vector_type(8))) short bf16x8;   // 8 bf16 (4 VGPRs)
typedef __attribute__((ext_vector_type(4))) float f32x4;

static inline int imin_h(int a, int b) { return a < b ? a : b; }

// ---- bf16 helpers (storage-only bf16; accumulation fp32) ----
__device__ __forceinline__ float bfu2f(uint32 u) { return __uint_as_float(u << 16); }
__device__ __forceinline__ u16 f2bf(float f) {
  uint32 x = __float_as_uint(f);
  x += 0x7fffu + ((x >> 16) & 1u);           // round-to-nearest-even
  return (u16)(x >> 16);
}
__device__ __forceinline__ uint32 pack2(float a, float b) {
  return (uint32)f2bf(a) | ((uint32)f2bf(b) << 16);
}

#define GLOBAL_AS(p) ((const __attribute__((address_space(1))) void*)(p))
#define LDS_AS(p)    ((__attribute__((address_space(3))) void*)(p))

// ---------------- misc ----------------
__global__ void k_zero(int* __restrict__ p, int n) {
  for (int i = blockIdx.x * blockDim.x + threadIdx.x; i < n; i += gridDim.x * blockDim.x)
    p[i] = 0;
}

// ---------------- CSR build (by dst) ----------------
__global__ void k_hist(const int* __restrict__ dst, int* __restrict__ deg, int E) {
  for (int e = blockIdx.x * blockDim.x + threadIdx.x; e < E; e += gridDim.x * blockDim.x)
    atomicAdd(&deg[dst[e]], 1);
}

// ---- 3-phase multi-block exclusive scan (chunk = 2048 = 256 thr x 8) ----
__global__ __launch_bounds__(256)
void k_scan1(const int* __restrict__ deg, int* __restrict__ bsum, int n) {
  __shared__ int sm[256];
  const int base = blockIdx.x * 2048 + threadIdx.x * 8;
  int s = 0;
  if (base + 8 <= n) {
    const uint4 a = *reinterpret_cast<const uint4*>(deg + base);
    const uint4 b = *reinterpret_cast<const uint4*>(deg + base + 4);
    s = (int)(a.x + a.y + a.z + a.w + b.x + b.y + b.z + b.w);
  } else {
    for (int i = 0; i < 8; ++i) if (base + i < n) s += deg[base + i];
  }
  sm[threadIdx.x] = s;
  __syncthreads();
  for (int off = 128; off > 0; off >>= 1) {
    if (threadIdx.x < off) sm[threadIdx.x] += sm[threadIdx.x + off];
    __syncthreads();
  }
  if (threadIdx.x == 0) bsum[blockIdx.x] = sm[0];
}

__global__ __launch_bounds__(256)
void k_scan2(int* __restrict__ bsum, int nb, int* __restrict__ rowptr, int n) {
  __shared__ int sm[256];
  const int v = (threadIdx.x < nb) ? bsum[threadIdx.x] : 0;
  sm[threadIdx.x] = v;
  __syncthreads();
  for (int off = 1; off < 256; off <<= 1) {
    const int t = (threadIdx.x >= off) ? sm[threadIdx.x - off] : 0;
    __syncthreads();
    sm[threadIdx.x] += t;
    __syncthreads();
  }
  if (threadIdx.x < nb) bsum[threadIdx.x] = sm[threadIdx.x] - v;  // exclusive
  if (threadIdx.x == nb - 1) rowptr[n] = sm[threadIdx.x];          // total = E
}

__global__ __launch_bounds__(256)
void k_scan3(const int* __restrict__ deg, const int* __restrict__ bsum,
             int* __restrict__ rowptr, int* __restrict__ cursor, int n) {
  __shared__ int sm[256];
  const int base = blockIdx.x * 2048 + threadIdx.x * 8;
  int v[8];
  int s = 0;
#pragma unroll
  for (int i = 0; i < 8; ++i) {
    v[i] = (base + i < n) ? deg[base + i] : 0;
    s += v[i];
  }
  sm[threadIdx.x] = s;
  __syncthreads();
  for (int off = 1; off < 256; off <<= 1) {
    const int t = (threadIdx.x >= off) ? sm[threadIdx.x - off] : 0;
    __syncthreads();
    sm[threadIdx.x] += t;
    __syncthreads();
  }
  int run = bsum[blockIdx.x] + sm[threadIdx.x] - s;   // exclusive prefix for this thread
#pragma unroll
  for (int i = 0; i < 8; ++i) {
    if (base + i < n) { rowptr[base + i] = run; cursor[base + i] = run; }
    run += v[i];
  }
}

__global__ void k_fill(const int* __restrict__ src, const int* __restrict__ dst,
                       int* __restrict__ cursor, int* __restrict__ col, int E) {
  for (int e = blockIdx.x * blockDim.x + threadIdx.x; e < E; e += gridDim.x * blockDim.x) {
    const int p = atomicAdd(&cursor[dst[e]], 1);
    col[p] = src[e];
  }
}

// ---------------- h0 = bf16(attr); masked rows = token ----------------
__global__ void k_cvt(const float4* __restrict__ in, uint2* __restrict__ out, int n4) {
  for (int i = blockIdx.x * blockDim.x + threadIdx.x; i < n4; i += gridDim.x * blockDim.x) {
    const float4 v = in[i];
    out[i] = make_uint2(pack2(v.x, v.y), pack2(v.z, v.w));
  }
}

__global__ void k_mask(const float4* __restrict__ token, const int* __restrict__ mask,
                       uint2* __restrict__ h0, int NM) {
  const int total = NM * (IN_DIM / 4);
  for (int i = blockIdx.x * blockDim.x + threadIdx.x; i < total; i += gridDim.x * blockDim.x) {
    const int m = i >> 5;
    const int c = i & 31;
    const float4 t = token[c];
    h0[(size_t)mask[m] * (IN_DIM / 4) + c] = make_uint2(pack2(t.x, t.y), pack2(t.z, t.w));
  }
}

// ------- weight transpose + convert + FRAGMENT-PACK ----------------------------------
// frag f = (n>>4)*(K/32) + (k>>5); u16 idx = f*512 + ((k>>3)&3)*128 + (n&15)*8 + (k&7).
__global__ void k_wt(const float* __restrict__ W, u16* __restrict__ Wt, int K, int Nn) {
  const int total = K * Nn;
  for (int t = blockIdx.x * blockDim.x + threadIdx.x; t < total; t += gridDim.x * blockDim.x) {
    const int n = t / K, k = t - n * K;
    const size_t idx = ((size_t)(n >> 4) * (K >> 5) + (k >> 5)) * 512 +
                       ((k >> 3) & 3) * 128 + ((n & 15) << 3) + (k & 7);
    Wt[idx] = f2bf(W[(size_t)k * Nn + n]);
  }
}

// -------- agg device body: mean over in-neighbors for one node (one wave) -------------
template <int D>
__device__ __forceinline__ void agg_node(const u16* __restrict__ h, const int* __restrict__ col,
                                         int beg, int end, int lane, u16* __restrict__ orow) {
  constexpr int V = D / 64;
  const size_t loff = (size_t)lane * V;
  float acc[V];
#pragma unroll
  for (int j = 0; j < V; ++j) acc[j] = 0.f;
  if constexpr (V == 8) {
    uint4 cur;
    if (beg < end) cur = *reinterpret_cast<const uint4*>(h + (size_t)col[beg] * D + loff);
    for (int e = beg; e < end; ++e) {
      uint4 nxt = cur;
      if (e + 1 < end)
        nxt = *reinterpret_cast<const uint4*>(h + (size_t)col[e + 1] * D + loff);
      acc[0] += bfu2f(cur.x & 0xffffu); acc[1] += bfu2f(cur.x >> 16);
      acc[2] += bfu2f(cur.y & 0xffffu); acc[3] += bfu2f(cur.y >> 16);
      acc[4] += bfu2f(cur.z & 0xffffu); acc[5] += bfu2f(cur.z >> 16);
      acc[6] += bfu2f(cur.w & 0xffffu); acc[7] += bfu2f(cur.w >> 16);
      cur = nxt;
    }
  } else {
    uint32 cur = 0;
    if (beg < end) cur = *reinterpret_cast<const uint32*>(h + (size_t)col[beg] * D + loff);
    for (int e = beg; e < end; ++e) {
      uint32 nxt = cur;
      if (e + 1 < end)
        nxt = *reinterpret_cast<const uint32*>(h + (size_t)col[e + 1] * D + loff);
      acc[0] += bfu2f(cur & 0xffffu); acc[1] += bfu2f(cur >> 16);
      cur = nxt;
    }
  }
  const float inv = 1.0f / fmaxf((float)(end - beg), 1.0f);
  u16* o = orow + loff;
  if constexpr (V == 8) {
    uint4 u;
    u.x = pack2(acc[0] * inv, acc[1] * inv);
    u.y = pack2(acc[2] * inv, acc[3] * inv);
    u.z = pack2(acc[4] * inv, acc[5] * inv);
    u.w = pack2(acc[6] * inv, acc[7] * inv);
    *reinterpret_cast<uint4*>(o) = u;
  } else {
    *reinterpret_cast<uint32*>(o) = pack2(acc[0] * inv, acc[1] * inv);
  }
}

// -------- standalone agg (1 wave/node, 256 thr) — used for L4 mask-restricted ---------
template <int D, bool REMAP>
__global__ __launch_bounds__(256)
void k_agg(const u16* __restrict__ h, const int* __restrict__ col,
           const int* __restrict__ rowptr, const int* __restrict__ nodes,
           u16* __restrict__ out, int n) {
  const int w = blockIdx.x * (blockDim.x >> 6) + (threadIdx.x >> 6);
  if (w >= n) return;
  const int node = REMAP ? nodes[w] : w;
  agg_node<D>(h, col, rowptr[node], rowptr[node + 1], threadIdx.x & 63,
              out + (size_t)w * D);
}

// ======== FUSED: gemm(chunk t-1) + agg(chunk t) in one launch ==========================
// Blocks [0, gemm_blocks): R13-proven 128x256 dual-A GEMM (single-barrier 3-deep
// pipeline, A+B staged via global_load_lds, fragment-linear LDS, coalesced epilogue).
// Blocks [gemm_blocks, ...): agg, 8 waves = 8 nodes/block. Disjoint resources
// (GEMM: LDS+MFMA; agg: HBM) -> overlap on co-resident CUs.
template <int DIN, bool RELU>
__global__ __launch_bounds__(512, 2)
void k_fused(const u16* __restrict__ hfull,      // full h (N x DIN) for agg gather
             const u16* __restrict__ A1,          // gemm self rows (chunk base)
             const u16* __restrict__ A2,          // gemm neigh rows (CH prev)
             u16* __restrict__ CHout,             // agg output (chunk t)
             const int* __restrict__ col,
             const int* __restrict__ rowptr_c,    // rowptr + agg chunk start
             const u16* __restrict__ Wt1, const u16* __restrict__ Wt2,
             const float* __restrict__ bias,
             u16* __restrict__ out,               // gemm output (chunk base)
             int n_agg, int M, int gemm_blocks) {
  constexpr int DOUT = HID;
  __shared__ char lds[73728];                 // gemm: 3 x 24KB pipeline / 8 x 9216B epi
  constexpr int KS = DIN / 32;
  constexpr int S  = 2 * KS;
  const int tid = threadIdx.x;
  const int w = tid >> 6, l = tid & 63;

  if ((int)blockIdx.x >= gemm_blocks) {
    // ---------------- agg path ----------------
    const int wl = ((int)blockIdx.x - gemm_blocks) * 8 + w;
    if (wl >= n_agg) return;
    agg_node<DIN>(hfull, col, rowptr_c[wl], rowptr_c[wl + 1], l, CHout + (size_t)wl * DIN);
    return;
  }

  // ---------------- gemm path (R13 body) ----------------
  const int l15 = l & 15, l4 = l >> 4;
  const int wm = w >> 2, wn = w & 3;          // 2 x 4 wave grid, wave tile 64x64

  const int nwg  = gemm_blocks;
  const int orig = blockIdx.x;
  const int q = nwg >> 3, r = nwg & 7;
  const int xcd = orig & 7, seq = orig >> 3;
  const int wg = (xcd < r ? xcd * (q + 1) : r * (q + 1) + (xcd - r) * q) + seq;
  const int mt = wg >> 1, nt = wg & 1;        // NT = 2
  const int m0 = mt * 128, n0 = nt * 256;

  f32x4 acc[4][4];
#pragma unroll
  for (int i = 0; i < 4; ++i)
#pragma unroll
    for (int j = 0; j < 4; ++j) acc[i][j] = (f32x4){0.f, 0.f, 0.f, 0.f};

  const int arow = min(m0 + w * 16 + l15, M - 1);
  const int kl = l4 * 8;
  const u16* pA1 = A1 + (size_t)arow * DIN + kl;
  const u16* pA2 = A2 + (size_t)arow * DIN + kl;
  const u16* bb1 = Wt1 + ((size_t)(n0 >> 4) + 2 * w) * KS * 512 + (size_t)l * 8;
  const u16* bb2 = Wt2 + ((size_t)(n0 >> 4) + 2 * w) * KS * 512 + (size_t)l * 8;

  auto stage = [&](int s) {                    // 3 global_load_lds per wave
    const int ph = s / KS;
    const int kf = s - ph * KS;
    char* buf = lds + (s % 3) * 24576;
    const u16* a0 = (ph ? pA2 : pA1) + kf * 32;
    const u16* b0 = (ph ? bb2 : bb1) + kf * 512;
    const u16* b1 = b0 + KS * 512;             // next n-frag
    __builtin_amdgcn_global_load_lds(GLOBAL_AS(a0), LDS_AS(buf + w * 1024), 16, 0, 0);
    __builtin_amdgcn_global_load_lds(GLOBAL_AS(b0), LDS_AS(buf + 8192 + (2 * w + 0) * 1024), 16, 0, 0);
    __builtin_amdgcn_global_load_lds(GLOBAL_AS(b1), LDS_AS(buf + 8192 + (2 * w + 1) * 1024), 16, 0, 0);
  };

  stage(0);
  stage(1);

#pragma unroll
  for (int s = 0; s < S; ++s) {
    if (s + 1 < S) asm volatile("s_waitcnt vmcnt(3)" ::: "memory");
    else           asm volatile("s_waitcnt vmcnt(0)" ::: "memory");
    __builtin_amdgcn_s_barrier();
    if (s + 2 < S) stage(s + 2);               // refills buf[(s-1)%3] — drained pre-barrier
    char* buf = lds + (s % 3) * 24576;
    bf16x8 af[4], bfr[4];
#pragma unroll
    for (int i = 0; i < 4; ++i)
      af[i] = *reinterpret_cast<const bf16x8*>(buf + (wm * 4 + i) * 1024 + l * 16);
#pragma unroll
    for (int j = 0; j < 4; ++j)
      bfr[j] = *reinterpret_cast<const bf16x8*>(buf + 8192 + (wn * 4 + j) * 1024 + l * 16);
#pragma unroll
    for (int i = 0; i < 4; ++i)
#pragma unroll
      for (int j = 0; j < 4; ++j)
        acc[i][j] = __builtin_amdgcn_mfma_f32_16x16x32_bf16(af[i], bfr[j], acc[i][j], 0, 0, 0);
    asm volatile("s_waitcnt lgkmcnt(0)" ::: "memory");   // reads of buf retired
  }
  __builtin_amdgcn_s_barrier();                // epilogue reuses pipeline LDS

  u16* eb = (u16*)(lds + w * 9216);
  float bv[4];
#pragma unroll
  for (int j = 0; j < 4; ++j) bv[j] = bias[n0 + wn * 64 + j * 16 + l15];
#pragma unroll
  for (int i = 0; i < 4; ++i)
#pragma unroll
    for (int j = 0; j < 4; ++j)
#pragma unroll
      for (int r2 = 0; r2 < 4; ++r2) {
        const int lr = i * 16 + l4 * 4 + r2;
        float t = acc[i][j][r2] + bv[j];
        if (RELU) t = fmaxf(t, 0.f);
        eb[lr * 72 + j * 16 + l15] = f2bf(t);
      }
  asm volatile("s_waitcnt lgkmcnt(0)" ::: "memory");      // wave-local write->read order
#pragma unroll
  for (int p = 0; p < 8; ++p) {
    const int lr = p * 8 + (l >> 3);
    const int row = m0 + wm * 64 + lr;
    if (row < M) {
      const uint4 v = *reinterpret_cast<const uint4*>(eb + lr * 72 + (l & 7) * 8);
      *reinterpret_cast<uint4*>(out + (size_t)row * DOUT + n0 + wn * 64 + (l & 7) * 8) = v;
    }
  }
}

// -------- 128x128 4-wave kernel (DOUT=128, A1-row remap — L4) --------------------------
template <int DIN, int DOUT, bool RELU, bool REMAP>
__global__ __launch_bounds__(256, 3)
void k_gemm(const u16* __restrict__ A1, const u16* __restrict__ A2,
            const u16* __restrict__ Wt1, const u16* __restrict__ Wt2,
            const float* __restrict__ bias, u16* __restrict__ out, int M,
            const int* __restrict__ remap) {
  __shared__ char lds[49152];
  constexpr int KS = DIN / 32;
  constexpr int S  = 2 * KS;
  const int tid = threadIdx.x;
  const int w = tid >> 6, l = tid & 63;
  const int l15 = l & 15, l4 = l >> 4;
  const int wm = w >> 1, wn = w & 1;

  const int nwg  = gridDim.x * gridDim.y;
  const int orig = blockIdx.x + gridDim.x * blockIdx.y;
  const int q = nwg >> 3, r = nwg & 7;
  const int xcd = orig & 7, seq = orig >> 3;
  const int wg = (xcd < r ? xcd * (q + 1) : r * (q + 1) + (xcd - r) * q) + seq;
  constexpr int NT = DOUT / 128;
  const int mt = wg / NT, nt = wg - mt * NT;
  const int m0 = mt * 128, n0 = nt * 128;

  f32x4 acc[4][4];
#pragma unroll
  for (int i = 0; i < 4; ++i)
#pragma unroll
    for (int j = 0; j < 4; ++j) acc[i][j] = (f32x4){0.f, 0.f, 0.f, 0.f};

  const int am0 = min(m0 + (2 * w) * 16 + l15, M - 1);
  const int am1 = min(m0 + (2 * w + 1) * 16 + l15, M - 1);
  const int ar0 = REMAP ? remap[am0] : am0;
  const int ar1 = REMAP ? remap[am1] : am1;
  const int kl = l4 * 8;
  const u16* pA1r0 = A1 + (size_t)ar0 * DIN + kl;
  const u16* pA1r1 = A1 + (size_t)ar1 * DIN + kl;
  const u16* pA2r0 = A2 + (size_t)am0 * DIN + kl;
  const u16* pA2r1 = A2 + (size_t)am1 * DIN + kl;
  const u16* bb1 = Wt1 + ((size_t)(n0 >> 4) + 2 * w) * KS * 512 + (size_t)l * 8;
  const u16* bb2 = Wt2 + ((size_t)(n0 >> 4) + 2 * w) * KS * 512 + (size_t)l * 8;

  auto stage = [&](int s) {
    const int ph = s / KS;
    const int kf = s - ph * KS;
    char* buf = lds + (s % 3) * 16384;
    const u16* a0 = (ph ? pA2r0 : pA1r0) + kf * 32;
    const u16* a1 = (ph ? pA2r1 : pA1r1) + kf * 32;
    const u16* b0 = (ph ? bb2 : bb1) + kf * 512;
    const u16* b1 = b0 + KS * 512;
    __builtin_amdgcn_global_load_lds(GLOBAL_AS(a0), LDS_AS(buf + (2 * w + 0) * 1024), 16, 0, 0);
    __builtin_amdgcn_global_load_lds(GLOBAL_AS(a1), LDS_AS(buf + (2 * w + 1) * 1024), 16, 0, 0);
    __builtin_amdgcn_global_load_lds(GLOBAL_AS(b0), LDS_AS(buf + 8192 + (2 * w + 0) * 1024), 16, 0, 0);
    __builtin_amdgcn_global_load_lds(GLOBAL_AS(b1), LDS_AS(buf + 8192 + (2 * w + 1) * 1024), 16, 0, 0);
  };

  stage(0);
  stage(1);

#pragma unroll
  for (int s = 0; s < S; ++s) {
    if (s + 1 < S) asm volatile("s_waitcnt vmcnt(4)" ::: "memory");
    else           asm volatile("s_waitcnt vmcnt(0)" ::: "memory");
    __builtin_amdgcn_s_barrier();
    if (s + 2 < S) stage(s + 2);
    char* buf = lds + (s % 3) * 16384;
    bf16x8 af[4], bfr[4];
#pragma unroll
    for (int i = 0; i < 4; ++i)
      af[i] = *reinterpret_cast<const bf16x8*>(buf + (wm * 4 + i) * 1024 + l * 16);
#pragma unroll
    for (int j = 0; j < 4; ++j)
      bfr[j] = *reinterpret_cast<const bf16x8*>(buf + 8192 + (wn * 4 + j) * 1024 + l * 16);
#pragma unroll
    for (int i = 0; i < 4; ++i)
#pragma unroll
      for (int j = 0; j < 4; ++j)
        acc[i][j] = __builtin_amdgcn_mfma_f32_16x16x32_bf16(af[i], bfr[j], acc[i][j], 0, 0, 0);
    asm volatile("s_waitcnt lgkmcnt(0)" ::: "memory");
  }

#pragma unroll
  for (int j = 0; j < 4; ++j) {
    const int c = n0 + wn * 64 + j * 16 + l15;
    const float bv = bias[c];
#pragma unroll
    for (int i = 0; i < 4; ++i) {
      const int rowb = m0 + wm * 64 + i * 16 + l4 * 4;
#pragma unroll
      for (int r2 = 0; r2 < 4; ++r2) {
        const int row = rowb + r2;
        if (row < M) {
          float t = acc[i][j][r2] + bv;
          if (RELU) t = fmaxf(t, 0.f);
          out[(size_t)row * DOUT + c] = f2bf(t);
        }
      }
    }
  }
}

// ---------------- loss (dec is COMPACT: NM x 128, slot m <-> node mask[m]) -------------
__global__ __launch_bounds__(256)
void k_loss1(const u16* __restrict__ dec, const float* __restrict__ attr,
             const int* __restrict__ mask, int NM, float* __restrict__ partials) {
  __shared__ float sm[256];
  float s = 0.f;
  const int total = NM * (IN_DIM / 4);
  for (int idx = blockIdx.x * blockDim.x + threadIdx.x; idx < total; idx += gridDim.x * blockDim.x) {
    const int m = idx >> 5, c = (idx & 31) * 4;
    const int node = mask[m];
    const float4 a = *reinterpret_cast<const float4*>(&attr[(size_t)node * IN_DIM + c]);
    const uint2 d2 = *reinterpret_cast<const uint2*>(&dec[(size_t)m * IN_DIM + c]);
    const float dx = bfu2f(d2.x & 0xffffu) - a.x;
    const float dy = bfu2f(d2.x >> 16)     - a.y;
    const float dz = bfu2f(d2.y & 0xffffu) - a.z;
    const float dw = bfu2f(d2.y >> 16)     - a.w;
    s += dx * dx + dy * dy + dz * dz + dw * dw;
  }
  sm[threadIdx.x] = s;
  __syncthreads();
  for (int off = 128; off > 0; off >>= 1) {
    if (threadIdx.x < off) sm[threadIdx.x] += sm[threadIdx.x + off];
    __syncthreads();
  }
  if (threadIdx.x == 0) partials[blockIdx.x] = sm[0];
}

__global__ __launch_bounds__(256)
void k_loss2(const float* __restrict__ partials, int nb, float* __restrict__ out, float inv) {
  __shared__ float sm[256];
  float s = 0.f;
  for (int i = threadIdx.x; i < nb; i += 256) s += partials[i];
  sm[threadIdx.x] = s;
  __syncthreads();
  for (int off = 128; off > 0; off >>= 1) {
    if (threadIdx.x < off) sm[threadIdx.x] += sm[threadIdx.x + off];
    __syncthreads();
  }
  if (threadIdx.x == 0) out[0] = sm[0] * inv;
}

// ---------------- launch ----------------
extern "C" void kernel_launch(void* const* d_in, const int* in_sizes, int n_in,
                              void* d_out, int out_size, void* d_ws, size_t ws_size,
                              hipStream_t stream) {
  const float* attr  = (const float*)d_in[0];
  const float* token = (const float*)d_in[1];
  const int*   src   = (const int*)d_in[2];
  const int*   dst   = (const int*)d_in[3];
  const int*   mask  = (const int*)d_in[4];
  const float* Wself[4]  = {(const float*)d_in[5], (const float*)d_in[8],
                            (const float*)d_in[11], (const float*)d_in[14]};
  const float* Wneigh[4] = {(const float*)d_in[6], (const float*)d_in[9],
                            (const float*)d_in[12], (const float*)d_in[15]};
  const float* Bias[4]   = {(const float*)d_in[7], (const float*)d_in[10],
                            (const float*)d_in[13], (const float*)d_in[16]};
  const int N  = in_sizes[0] / IN_DIM;
  const int E  = in_sizes[2];
  const int NM = in_sizes[4];

  size_t off = 0;
  auto take = [&](size_t bytes) -> void* {
    void* p = (char*)d_ws + off;
    off += (bytes + 255) & ~(size_t)255;
    return p;
  };
  u16* HA = (u16*)take((size_t)N * HID * sizeof(u16));   // 51.2 MB
  u16* HB = (u16*)take((size_t)N * HID * sizeof(u16));   // 51.2 MB
  const int dims_in[4]  = {IN_DIM, HID, HID, HID};
  const int dims_out[4] = {HID, HID, HID, IN_DIM};
  u16* WtS[4]; u16* WtN[4];
  for (int i = 0; i < 4; ++i) {
    WtS[i] = (u16*)take((size_t)dims_in[i] * dims_out[i] * sizeof(u16));
    WtN[i] = (u16*)take((size_t)dims_in[i] * dims_out[i] * sizeof(u16));
  }
  int* deg    = (int*)take((size_t)N * sizeof(int));
  int* rowptr = (int*)take((size_t)(N + 1) * sizeof(int));
  int* cursor = (int*)take((size_t)N * sizeof(int));
  int* col    = (int*)take((size_t)E * sizeof(int));
  int* bsum   = (int*)take(256 * sizeof(int));
  float* partials = (float*)take(512 * sizeof(float));

  // chunking for fused pipeline: C chunks rounded to 256 rows
  const int C = 4;
  int cstart[C + 1];
  const int cbase = ((N / C) + 255) & ~255;
  for (int i = 0; i <= C; ++i) cstart[i] = imin_h(i * cbase, N);
  // CH ping-pong buffers (chunk_max x 512)
  u16* CH0 = (u16*)take((size_t)cbase * HID * sizeof(u16));
  u16* CH1 = (u16*)take((size_t)cbase * HID * sizeof(u16));
  u16* CHp[2] = {CH0, CH1};
  u16* DEC = HA;                               // decoded compact (NM x 128) reuses HA

  // CSR build (multi-block 3-phase scan)
  k_zero<<<imin_h((N + 255) / 256, 1024), 256, 0, stream>>>(deg, N);
  const int eb = imin_h((E + 255) / 256, 4096);
  k_hist<<<eb, 256, 0, stream>>>(dst, deg, E);
  const int nb = (N + 2047) / 2048;
  k_scan1<<<nb, 256, 0, stream>>>(deg, bsum, N);
  k_scan2<<<1, 256, 0, stream>>>(bsum, nb, rowptr, N);
  k_scan3<<<nb, 256, 0, stream>>>(deg, bsum, rowptr, cursor, N);
  k_fill<<<eb, 256, 0, stream>>>(src, dst, cursor, col, E);

  // weights: transpose + bf16 + fragment-pack once per call
  for (int i = 0; i < 4; ++i) {
    const int tot = dims_in[i] * dims_out[i];
    k_wt<<<imin_h((tot + 255) / 256, 2048), 256, 0, stream>>>(Wself[i],  WtS[i], dims_in[i], dims_out[i]);
    k_wt<<<imin_h((tot + 255) / 256, 2048), 256, 0, stream>>>(Wneigh[i], WtN[i], dims_in[i], dims_out[i]);
  }

  // h0 = bf16(attr) with masked rows = token   (in HA as N x 128)
  const int n4 = N * (IN_DIM / 4);
  k_cvt<<<imin_h((n4 + 255) / 256, 2048), 256, 0, stream>>>((const float4*)attr, (uint2*)HA, n4);
  k_mask<<<imin_h((NM * (IN_DIM / 4) + 255) / 256, 2048), 256, 0, stream>>>(
      (const float4*)token, mask, (uint2*)HA, NM);

  // L1..L3: chunk-pipelined fused launches — launch t = { gemm(chunk t-1) + agg(chunk t) }
  auto run_layer = [&](const u16* hin, u16* hout, int din, int layer, bool relu) {
    for (int t = 0; t <= C; ++t) {
      const int a0 = (t < C) ? cstart[t] : 0;
      const int an = (t < C) ? (cstart[t + 1] - cstart[t]) : 0;
      const int g0 = (t > 0) ? cstart[t - 1] : 0;
      const int gm = (t > 0) ? (cstart[t] - cstart[t - 1]) : 0;
      const int gb = (t > 0) ? ((gm + 127) / 128) * 2 : 0;
      const int ab = (an + 7) / 8;
      const int total = gb + ab;
      if (total == 0) continue;
      u16* cha = CHp[t & 1];
      const u16* chg = CHp[(t ^ 1) & 1];
      const u16* a1 = hin + (size_t)g0 * din;
      u16* o = hout + (size_t)g0 * HID;
      if (din == IN_DIM)
        k_fused<IN_DIM, true><<<total, 512, 0, stream>>>(
            hin, a1, chg, cha, col, rowptr + a0,
            WtS[layer], WtN[layer], Bias[layer], o, an, gm, gb);
      else if (relu)
        k_fused<HID, true><<<total, 512, 0, stream>>>(
            hin, a1, chg, cha, col, rowptr + a0,
            WtS[layer], WtN[layer], Bias[layer], o, an, gm, gb);
      else
        k_fused<HID, false><<<total, 512, 0, stream>>>(
            hin, a1, chg, cha, col, rowptr + a0,
            WtS[layer], WtN[layer], Bias[layer], o, an, gm, gb);
    }
  };

  run_layer(HA, HB, IN_DIM, 0, true);   // L1: 128->512 relu   (HA h0 -> HB h1)
  run_layer(HB, HA, HID,    1, false);  // L2: 512->512        (HB h1 -> HA h2)
  run_layer(HA, HB, HID,    2, true);   // L3: 512->512 relu   (HA h2 -> HB h3)

  // L4 mask-restricted: decoded only at mask nodes (compact NM rows); CH0 big enough
  k_agg<HID, true><<<(NM + 3) / 4, 256, 0, stream>>>(HB, col, rowptr, mask, CH0, NM);
  k_gemm<HID, IN_DIM, false, true><<<dim3(1, (NM + 127) / 128), 256, 0, stream>>>(
      HB, CH0, WtS[3], WtN[3], Bias[3], DEC, NM, mask);

  // loss = mean((decoded[mask] - attr[mask])^2)
  k_loss1<<<512, 256, 0, stream>>>(DEC, attr, mask, NM, partials);
  k_loss2<<<1, 256, 0, stream>>>(partials, 512, (float*)d_out, 1.0f / ((float)NM * IN_DIM));
}

// Round 16
// 467.471 us; speedup vs baseline: 1.5129x; 1.5129x over previous
//
#include <hip/hip_runtime.h>
#include <cstdint>
#include <cstddef>

#define IN_DIM 128
#define HID    512

typedef unsigned int   uint32;
typedef unsigned short u16;
typedef __attribute__((ext_vector_type(8))) short bf16x8;   // 8 bf16 (4 VGPRs)
typedef __attribute__((ext_vector_type(4))) float f32x4;

static inline int imin_h(int a, int b) { return a < b ? a : b; }

// ---- bf16 helpers (storage-only bf16; accumulation fp32) ----
__device__ __forceinline__ float bfu2f(uint32 u) { return __uint_as_float(u << 16); }
__device__ __forceinline__ u16 f2bf(float f) {
  uint32 x = __float_as_uint(f);
  x += 0x7fffu + ((x >> 16) & 1u);           // round-to-nearest-even
  return (u16)(x >> 16);
}
__device__ __forceinline__ uint32 pack2(float a, float b) {
  return (uint32)f2bf(a) | ((uint32)f2bf(b) << 16);
}

#define GLOBAL_AS(p) ((const __attribute__((address_space(1))) void*)(p))
#define LDS_AS(p)    ((__attribute__((address_space(3))) void*)(p))

// ---------------- misc ----------------
__global__ void k_zero(int* __restrict__ p, int n) {
  for (int i = blockIdx.x * blockDim.x + threadIdx.x; i < n; i += gridDim.x * blockDim.x)
    p[i] = 0;
}

// ---------------- CSR build (by dst) ----------------
__global__ void k_hist(const int* __restrict__ dst, int* __restrict__ deg, int E) {
  for (int e = blockIdx.x * blockDim.x + threadIdx.x; e < E; e += gridDim.x * blockDim.x)
    atomicAdd(&deg[dst[e]], 1);
}

// ---- 3-phase multi-block exclusive scan (chunk = 2048 = 256 thr x 8) ----
__global__ __launch_bounds__(256)
void k_scan1(const int* __restrict__ deg, int* __restrict__ bsum, int n) {
  __shared__ int sm[256];
  const int base = blockIdx.x * 2048 + threadIdx.x * 8;
  int s = 0;
  if (base + 8 <= n) {
    const uint4 a = *reinterpret_cast<const uint4*>(deg + base);
    const uint4 b = *reinterpret_cast<const uint4*>(deg + base + 4);
    s = (int)(a.x + a.y + a.z + a.w + b.x + b.y + b.z + b.w);
  } else {
    for (int i = 0; i < 8; ++i) if (base + i < n) s += deg[base + i];
  }
  sm[threadIdx.x] = s;
  __syncthreads();
  for (int off = 128; off > 0; off >>= 1) {
    if (threadIdx.x < off) sm[threadIdx.x] += sm[threadIdx.x + off];
    __syncthreads();
  }
  if (threadIdx.x == 0) bsum[blockIdx.x] = sm[0];
}

__global__ __launch_bounds__(256)
void k_scan2(int* __restrict__ bsum, int nb, int* __restrict__ rowptr, int n) {
  __shared__ int sm[256];
  const int v = (threadIdx.x < nb) ? bsum[threadIdx.x] : 0;
  sm[threadIdx.x] = v;
  __syncthreads();
  for (int off = 1; off < 256; off <<= 1) {
    const int t = (threadIdx.x >= off) ? sm[threadIdx.x - off] : 0;
    __syncthreads();
    sm[threadIdx.x] += t;
    __syncthreads();
  }
  if (threadIdx.x < nb) bsum[threadIdx.x] = sm[threadIdx.x] - v;  // exclusive
  if (threadIdx.x == nb - 1) rowptr[n] = sm[threadIdx.x];          // total = E
}

__global__ __launch_bounds__(256)
void k_scan3(const int* __restrict__ deg, const int* __restrict__ bsum,
             int* __restrict__ rowptr, int* __restrict__ cursor, int n) {
  __shared__ int sm[256];
  const int base = blockIdx.x * 2048 + threadIdx.x * 8;
  int v[8];
  int s = 0;
#pragma unroll
  for (int i = 0; i < 8; ++i) {
    v[i] = (base + i < n) ? deg[base + i] : 0;
    s += v[i];
  }
  sm[threadIdx.x] = s;
  __syncthreads();
  for (int off = 1; off < 256; off <<= 1) {
    const int t = (threadIdx.x >= off) ? sm[threadIdx.x - off] : 0;
    __syncthreads();
    sm[threadIdx.x] += t;
    __syncthreads();
  }
  int run = bsum[blockIdx.x] + sm[threadIdx.x] - s;   // exclusive prefix for this thread
#pragma unroll
  for (int i = 0; i < 8; ++i) {
    if (base + i < n) { rowptr[base + i] = run; cursor[base + i] = run; }
    run += v[i];
  }
}

__global__ void k_fill(const int* __restrict__ src, const int* __restrict__ dst,
                       int* __restrict__ cursor, int* __restrict__ col, int E) {
  for (int e = blockIdx.x * blockDim.x + threadIdx.x; e < E; e += gridDim.x * blockDim.x) {
    const int p = atomicAdd(&cursor[dst[e]], 1);
    col[p] = src[e];
  }
}

// ---------------- h0 = bf16(attr); masked rows = token ----------------
__global__ void k_cvt(const float4* __restrict__ in, uint2* __restrict__ out, int n4) {
  for (int i = blockIdx.x * blockDim.x + threadIdx.x; i < n4; i += gridDim.x * blockDim.x) {
    const float4 v = in[i];
    out[i] = make_uint2(pack2(v.x, v.y), pack2(v.z, v.w));
  }
}

__global__ void k_mask(const float4* __restrict__ token, const int* __restrict__ mask,
                       uint2* __restrict__ h0, int NM) {
  const int total = NM * (IN_DIM / 4);
  for (int i = blockIdx.x * blockDim.x + threadIdx.x; i < total; i += gridDim.x * blockDim.x) {
    const int m = i >> 5;
    const int c = i & 31;
    const float4 t = token[c];
    h0[(size_t)mask[m] * (IN_DIM / 4) + c] = make_uint2(pack2(t.x, t.y), pack2(t.z, t.w));
  }
}

// ------- weight transpose + convert + FRAGMENT-PACK ----------------------------------
// frag f = (n>>4)*(K/32) + (k>>5); u16 idx = f*512 + ((k>>3)&3)*128 + (n&15)*8 + (k&7).
__global__ void k_wt(const float* __restrict__ W, u16* __restrict__ Wt, int K, int Nn) {
  const int total = K * Nn;
  for (int t = blockIdx.x * blockDim.x + threadIdx.x; t < total; t += gridDim.x * blockDim.x) {
    const int n = t / K, k = t - n * K;
    const size_t idx = ((size_t)(n >> 4) * (K >> 5) + (k >> 5)) * 512 +
                       ((k >> 3) & 3) * 128 + ((n & 15) << 3) + (k & 7);
    Wt[idx] = f2bf(W[(size_t)k * Nn + n]);
  }
}

// -------- mean aggregation over in-neighbors (CSR gather, 1 wave/node, 2-deep) --------
template <int D, bool REMAP>
__global__ __launch_bounds__(256)
void k_agg(const u16* __restrict__ h, const int* __restrict__ col,
           const int* __restrict__ rowptr, const int* __restrict__ nodes,
           u16* __restrict__ out, int n) {
  constexpr int V = D / 64;
  const int w = blockIdx.x * (blockDim.x >> 6) + (threadIdx.x >> 6);
  if (w >= n) return;
  const int node = REMAP ? nodes[w] : w;
  const int lane = threadIdx.x & 63;
  const int beg = rowptr[node], end = rowptr[node + 1];
  const size_t loff = (size_t)lane * V;
  float acc[V];
#pragma unroll
  for (int j = 0; j < V; ++j) acc[j] = 0.f;
  if constexpr (V == 8) {
    uint4 cur;
    if (beg < end) cur = *reinterpret_cast<const uint4*>(h + (size_t)col[beg] * D + loff);
    for (int e = beg; e < end; ++e) {
      uint4 nxt = cur;
      if (e + 1 < end)
        nxt = *reinterpret_cast<const uint4*>(h + (size_t)col[e + 1] * D + loff);
      acc[0] += bfu2f(cur.x & 0xffffu); acc[1] += bfu2f(cur.x >> 16);
      acc[2] += bfu2f(cur.y & 0xffffu); acc[3] += bfu2f(cur.y >> 16);
      acc[4] += bfu2f(cur.z & 0xffffu); acc[5] += bfu2f(cur.z >> 16);
      acc[6] += bfu2f(cur.w & 0xffffu); acc[7] += bfu2f(cur.w >> 16);
      cur = nxt;
    }
  } else {
    uint32 cur = 0;
    if (beg < end) cur = *reinterpret_cast<const uint32*>(h + (size_t)col[beg] * D + loff);
    for (int e = beg; e < end; ++e) {
      uint32 nxt = cur;
      if (e + 1 < end)
        nxt = *reinterpret_cast<const uint32*>(h + (size_t)col[e + 1] * D + loff);
      acc[0] += bfu2f(cur & 0xffffu); acc[1] += bfu2f(cur >> 16);
      cur = nxt;
    }
  }
  const float inv = 1.0f / fmaxf((float)(end - beg), 1.0f);
  u16* o = out + (size_t)w * D + loff;
  if constexpr (V == 8) {
    uint4 u;
    u.x = pack2(acc[0] * inv, acc[1] * inv);
    u.y = pack2(acc[2] * inv, acc[3] * inv);
    u.z = pack2(acc[4] * inv, acc[5] * inv);
    u.w = pack2(acc[6] * inv, acc[7] * inv);
    *reinterpret_cast<uint4*>(o) = u;
  } else {
    *reinterpret_cast<uint32*>(o) = pack2(acc[0] * inv, acc[1] * inv);
  }
}

// ======== dual-A bf16 MFMA GEMM: 128x256 tile, 8 waves of 64x64 (R13-verified) =========
// SINGLE-barrier K-loop: vmcnt(3) -> barrier -> stage(s+2) -> ds_read+MFMA -> lgkmcnt(0).
// 3 x 24KB rotating LDS; coalesced bf16 epilogue via LDS (72-u16 padded rows).
template <int DIN, bool RELU>
__global__ __launch_bounds__(512, 4)
void k_gemm_big(const u16* __restrict__ A1, const u16* __restrict__ A2,
                const u16* __restrict__ Wt1, const u16* __restrict__ Wt2,
                const float* __restrict__ bias, u16* __restrict__ out, int M) {
  constexpr int DOUT = HID;
  __shared__ char lds[73728];                 // 3 x (A 8KB + B 16KB); epilogue: 8 x 9216B
  constexpr int KS = DIN / 32;                // k-frags per phase
  constexpr int S  = 2 * KS;                  // total K-steps (dual-A)
  const int tid = threadIdx.x;
  const int w = tid >> 6, l = tid & 63;
  const int l15 = l & 15, l4 = l >> 4;
  const int wm = w >> 2, wn = w & 3;          // 2 x 4 wave grid, wave tile 64x64

  // bijective XCD swizzle (m204); n-tile fastest
  const int nwg  = gridDim.x * gridDim.y;
  const int orig = blockIdx.x + gridDim.x * blockIdx.y;
  const int q = nwg >> 3, r = nwg & 7;
  const int xcd = orig & 7, seq = orig >> 3;
  const int wg = (xcd < r ? xcd * (q + 1) : r * (q + 1) + (xcd - r) * q) + seq;
  const int mt = wg >> 1, nt = wg & 1;        // NT = 2
  const int m0 = mt * 128, n0 = nt * 256;

  f32x4 acc[4][4];
#pragma unroll
  for (int i = 0; i < 4; ++i)
#pragma unroll
    for (int j = 0; j < 4; ++j) acc[i][j] = (f32x4){0.f, 0.f, 0.f, 0.f};

  // A staging: wave w stages m-frag w (rows m0 + w*16 + l15)
  const int arow = min(m0 + w * 16 + l15, M - 1);
  const int kl = l4 * 8;
  const u16* pA1 = A1 + (size_t)arow * DIN + kl;
  const u16* pA2 = A2 + (size_t)arow * DIN + kl;
  // B staging (fragment-packed): wave w stages n-frags {2w, 2w+1}
  const u16* bb1 = Wt1 + ((size_t)(n0 >> 4) + 2 * w) * KS * 512 + (size_t)l * 8;
  const u16* bb2 = Wt2 + ((size_t)(n0 >> 4) + 2 * w) * KS * 512 + (size_t)l * 8;

  auto stage = [&](int s) {                    // 3 global_load_lds per wave
    const int ph = s / KS;
    const int kf = s - ph * KS;
    char* buf = lds + (s % 3) * 24576;
    const u16* a0 = (ph ? pA2 : pA1) + kf * 32;
    const u16* b0 = (ph ? bb2 : bb1) + kf * 512;
    const u16* b1 = b0 + KS * 512;             // next n-frag
    __builtin_amdgcn_global_load_lds(GLOBAL_AS(a0), LDS_AS(buf + w * 1024), 16, 0, 0);
    __builtin_amdgcn_global_load_lds(GLOBAL_AS(b0), LDS_AS(buf + 8192 + (2 * w + 0) * 1024), 16, 0, 0);
    __builtin_amdgcn_global_load_lds(GLOBAL_AS(b1), LDS_AS(buf + 8192 + (2 * w + 1) * 1024), 16, 0, 0);
  };

  stage(0);
  stage(1);

#pragma unroll
  for (int s = 0; s < S; ++s) {
    // own 3 loads for buf[s] done; next stage's 3 may stay in flight
    if (s + 1 < S) asm volatile("s_waitcnt vmcnt(3)" ::: "memory");
    else           asm volatile("s_waitcnt vmcnt(0)" ::: "memory");
    __builtin_amdgcn_s_barrier();
    if (s + 2 < S) stage(s + 2);               // refills buf[(s-1)%3] — drained pre-barrier
    char* buf = lds + (s % 3) * 24576;
    bf16x8 af[4], bfr[4];
#pragma unroll
    for (int i = 0; i < 4; ++i)
      af[i] = *reinterpret_cast<const bf16x8*>(buf + (wm * 4 + i) * 1024 + l * 16);
#pragma unroll
    for (int j = 0; j < 4; ++j)
      bfr[j] = *reinterpret_cast<const bf16x8*>(buf + 8192 + (wn * 4 + j) * 1024 + l * 16);
#pragma unroll
    for (int i = 0; i < 4; ++i)
#pragma unroll
      for (int j = 0; j < 4; ++j)
        acc[i][j] = __builtin_amdgcn_mfma_f32_16x16x32_bf16(af[i], bfr[j], acc[i][j], 0, 0, 0);
    asm volatile("s_waitcnt lgkmcnt(0)" ::: "memory");   // reads of buf retired
  }
  __builtin_amdgcn_s_barrier();                // epilogue reuses pipeline LDS

  // ---- coalesced epilogue: C/D (col=lane&15, row=(lane>>4)*4+reg) -> LDS -> global ----
  u16* eb = (u16*)(lds + w * 9216);
  float bv[4];
#pragma unroll
  for (int j = 0; j < 4; ++j) bv[j] = bias[n0 + wn * 64 + j * 16 + l15];
#pragma unroll
  for (int i = 0; i < 4; ++i)
#pragma unroll
    for (int j = 0; j < 4; ++j)
#pragma unroll
      for (int r = 0; r < 4; ++r) {
        const int lr = i * 16 + l4 * 4 + r;
        float t = acc[i][j][r] + bv[j];
        if (RELU) t = fmaxf(t, 0.f);
        eb[lr * 72 + j * 16 + l15] = f2bf(t);
      }
  asm volatile("s_waitcnt lgkmcnt(0)" ::: "memory");      // wave-local write->read order
#pragma unroll
  for (int p = 0; p < 8; ++p) {
    const int lr = p * 8 + (l >> 3);
    const int row = m0 + wm * 64 + lr;
    if (row < M) {
      const uint4 v = *reinterpret_cast<const uint4*>(eb + lr * 72 + (l & 7) * 8);
      *reinterpret_cast<uint4*>(out + (size_t)row * DOUT + n0 + wn * 64 + (l & 7) * 8) = v;
    }
  }
}

// -------- L4 fused: 128x128 4-wave GEMM (A1-row remap) + MSE loss accumulation ---------
// decoded (bf16-rounded, matching prior verified numerics) is never written to memory:
// each thread squares its outputs against attr[mask[row]], block-reduce, one atomicAdd.
template <int DIN, int DOUT>
__global__ __launch_bounds__(256, 3)
void k_gemm_loss(const u16* __restrict__ A1, const u16* __restrict__ A2,
                 const u16* __restrict__ Wt1, const u16* __restrict__ Wt2,
                 const float* __restrict__ bias, const float* __restrict__ attr,
                 float* __restrict__ partials, int M, const int* __restrict__ remap) {
  __shared__ char lds[49152];
  constexpr int KS = DIN / 32;
  constexpr int S  = 2 * KS;
  const int tid = threadIdx.x;
  const int w = tid >> 6, l = tid & 63;
  const int l15 = l & 15, l4 = l >> 4;
  const int wm = w >> 1, wn = w & 1;

  const int nwg  = gridDim.x * gridDim.y;
  const int orig = blockIdx.x + gridDim.x * blockIdx.y;
  const int q = nwg >> 3, r = nwg & 7;
  const int xcd = orig & 7, seq = orig >> 3;
  const int wg = (xcd < r ? xcd * (q + 1) : r * (q + 1) + (xcd - r) * q) + seq;
  constexpr int NT = DOUT / 128;
  const int mt = wg / NT, nt = wg - mt * NT;
  const int m0 = mt * 128, n0 = nt * 128;

  f32x4 acc[4][4];
#pragma unroll
  for (int i = 0; i < 4; ++i)
#pragma unroll
    for (int j = 0; j < 4; ++j) acc[i][j] = (f32x4){0.f, 0.f, 0.f, 0.f};

  const int am0 = min(m0 + (2 * w) * 16 + l15, M - 1);
  const int am1 = min(m0 + (2 * w + 1) * 16 + l15, M - 1);
  const int ar0 = remap[am0];
  const int ar1 = remap[am1];
  const int kl = l4 * 8;
  const u16* pA1r0 = A1 + (size_t)ar0 * DIN + kl;
  const u16* pA1r1 = A1 + (size_t)ar1 * DIN + kl;
  const u16* pA2r0 = A2 + (size_t)am0 * DIN + kl;
  const u16* pA2r1 = A2 + (size_t)am1 * DIN + kl;
  const u16* bb1 = Wt1 + ((size_t)(n0 >> 4) + 2 * w) * KS * 512 + (size_t)l * 8;
  const u16* bb2 = Wt2 + ((size_t)(n0 >> 4) + 2 * w) * KS * 512 + (size_t)l * 8;

  auto stage = [&](int s) {
    const int ph = s / KS;
    const int kf = s - ph * KS;
    char* buf = lds + (s % 3) * 16384;
    const u16* a0 = (ph ? pA2r0 : pA1r0) + kf * 32;
    const u16* a1 = (ph ? pA2r1 : pA1r1) + kf * 32;
    const u16* b0 = (ph ? bb2 : bb1) + kf * 512;
    const u16* b1 = b0 + KS * 512;
    __builtin_amdgcn_global_load_lds(GLOBAL_AS(a0), LDS_AS(buf + (2 * w + 0) * 1024), 16, 0, 0);
    __builtin_amdgcn_global_load_lds(GLOBAL_AS(a1), LDS_AS(buf + (2 * w + 1) * 1024), 16, 0, 0);
    __builtin_amdgcn_global_load_lds(GLOBAL_AS(b0), LDS_AS(buf + 8192 + (2 * w + 0) * 1024), 16, 0, 0);
    __builtin_amdgcn_global_load_lds(GLOBAL_AS(b1), LDS_AS(buf + 8192 + (2 * w + 1) * 1024), 16, 0, 0);
  };

  stage(0);
  stage(1);

#pragma unroll
  for (int s = 0; s < S; ++s) {
    if (s + 1 < S) asm volatile("s_waitcnt vmcnt(4)" ::: "memory");
    else           asm volatile("s_waitcnt vmcnt(0)" ::: "memory");
    __builtin_amdgcn_s_barrier();
    if (s + 2 < S) stage(s + 2);
    char* buf = lds + (s % 3) * 16384;
    bf16x8 af[4], bfr[4];
#pragma unroll
    for (int i = 0; i < 4; ++i)
      af[i] = *reinterpret_cast<const bf16x8*>(buf + (wm * 4 + i) * 1024 + l * 16);
#pragma unroll
    for (int j = 0; j < 4; ++j)
      bfr[j] = *reinterpret_cast<const bf16x8*>(buf + 8192 + (wn * 4 + j) * 1024 + l * 16);
#pragma unroll
    for (int i = 0; i < 4; ++i)
#pragma unroll
      for (int j = 0; j < 4; ++j)
        acc[i][j] = __builtin_amdgcn_mfma_f32_16x16x32_bf16(af[i], bfr[j], acc[i][j], 0, 0, 0);
    asm volatile("s_waitcnt lgkmcnt(0)" ::: "memory");
  }

  // ---- fused loss epilogue: sum (bf16(acc+bias) - attr[mask[row]])^2 ----
  float lsum = 0.f;
#pragma unroll
  for (int j = 0; j < 4; ++j) {
    const int c = n0 + wn * 64 + j * 16 + l15;
    const float bv = bias[c];
#pragma unroll
    for (int i = 0; i < 4; ++i) {
      const int rowb = m0 + wm * 64 + i * 16 + l4 * 4;
#pragma unroll
      for (int r2 = 0; r2 < 4; ++r2) {
        const int row = rowb + r2;
        if (row < M) {
          const float t = bfu2f((uint32)f2bf(acc[i][j][r2] + bv));  // keep bf16 rounding
          const float d = t - attr[(size_t)remap[row] * IN_DIM + c];
          lsum += d * d;
        }
      }
    }
  }
  __syncthreads();                       // pipeline LDS reads done; reuse as reduce buf
  float* sm = (float*)lds;
  sm[tid] = lsum;
  __syncthreads();
  for (int off2 = 128; off2 > 0; off2 >>= 1) {
    if (tid < off2) sm[tid] += sm[tid + off2];
    __syncthreads();
  }
  if (tid == 0) atomicAdd(&partials[0], sm[0]);
}

// ---------------- finalize: out = partials[0] / (NM*128) ----------------
__global__ void k_final(const float* __restrict__ partials, float* __restrict__ out, float inv) {
  out[0] = partials[0] * inv;
}

// ---------------- launch ----------------
extern "C" void kernel_launch(void* const* d_in, const int* in_sizes, int n_in,
                              void* d_out, int out_size, void* d_ws, size_t ws_size,
                              hipStream_t stream) {
  const float* attr  = (const float*)d_in[0];
  const float* token = (const float*)d_in[1];
  const int*   src   = (const int*)d_in[2];
  const int*   dst   = (const int*)d_in[3];
  const int*   mask  = (const int*)d_in[4];
  const float* Wself[4]  = {(const float*)d_in[5], (const float*)d_in[8],
                            (const float*)d_in[11], (const float*)d_in[14]};
  const float* Wneigh[4] = {(const float*)d_in[6], (const float*)d_in[9],
                            (const float*)d_in[12], (const float*)d_in[15]};
  const float* Bias[4]   = {(const float*)d_in[7], (const float*)d_in[10],
                            (const float*)d_in[13], (const float*)d_in[16]};
  const int N  = in_sizes[0] / IN_DIM;
  const int E  = in_sizes[2];
  const int NM = in_sizes[4];

  size_t off = 0;
  auto take = [&](size_t bytes) -> void* {
    void* p = (char*)d_ws + off;
    off += (bytes + 255) & ~(size_t)255;
    return p;
  };
  u16* HA = (u16*)take((size_t)N * HID * sizeof(u16));   // 51.2 MB
  u16* HB = (u16*)take((size_t)N * HID * sizeof(u16));   // 51.2 MB
  const int dims_in[4]  = {IN_DIM, HID, HID, HID};
  const int dims_out[4] = {HID, HID, HID, IN_DIM};
  u16* WtS[4]; u16* WtN[4];
  for (int i = 0; i < 4; ++i) {
    WtS[i] = (u16*)take((size_t)dims_in[i] * dims_out[i] * sizeof(u16));
    WtN[i] = (u16*)take((size_t)dims_in[i] * dims_out[i] * sizeof(u16));
  }
  int* deg    = (int*)take((size_t)N * sizeof(int));
  int* rowptr = (int*)take((size_t)(N + 1) * sizeof(int));
  int* cursor = (int*)take((size_t)N * sizeof(int));
  int* col    = (int*)take((size_t)E * sizeof(int));
  int* bsum   = (int*)take(256 * sizeof(int));
  float* partials = (float*)take(512 * sizeof(float));

  // agg chunk: one chunk covering N (rounded to 256)
  size_t rem = (ws_size > off + 4096) ? (ws_size - off - 4096) : 0;
  const int cap = (int)(rem / ((size_t)HID * sizeof(u16)));
  const int want = (N + 255) & ~255;
  int chunk = (cap >= want) ? want : (cap & ~255);
  if (chunk < 2048) chunk = 2048;
  u16* CH = (u16*)take((size_t)chunk * HID * sizeof(u16));

  // CSR build (multi-block 3-phase scan) + zero loss accumulator
  k_zero<<<imin_h((N + 255) / 256, 1024), 256, 0, stream>>>(deg, N);
  k_zero<<<1, 256, 0, stream>>>((int*)partials, 512);
  const int eb = imin_h((E + 255) / 256, 4096);
  k_hist<<<eb, 256, 0, stream>>>(dst, deg, E);
  const int nb = (N + 2047) / 2048;
  k_scan1<<<nb, 256, 0, stream>>>(deg, bsum, N);
  k_scan2<<<1, 256, 0, stream>>>(bsum, nb, rowptr, N);
  k_scan3<<<nb, 256, 0, stream>>>(deg, bsum, rowptr, cursor, N);
  k_fill<<<eb, 256, 0, stream>>>(src, dst, cursor, col, E);

  // weights: transpose + bf16 + fragment-pack once per call
  for (int i = 0; i < 4; ++i) {
    const int tot = dims_in[i] * dims_out[i];
    k_wt<<<imin_h((tot + 255) / 256, 2048), 256, 0, stream>>>(Wself[i],  WtS[i], dims_in[i], dims_out[i]);
    k_wt<<<imin_h((tot + 255) / 256, 2048), 256, 0, stream>>>(Wneigh[i], WtN[i], dims_in[i], dims_out[i]);
  }

  // h0 = bf16(attr) with masked rows = token   (in HA as N x 128)
  const int n4 = N * (IN_DIM / 4);
  k_cvt<<<imin_h((n4 + 255) / 256, 2048), 256, 0, stream>>>((const float4*)attr, (uint2*)HA, n4);
  k_mask<<<imin_h((NM * (IN_DIM / 4) + 255) / 256, 2048), 256, 0, stream>>>(
      (const float4*)token, mask, (uint2*)HA, NM);

  // L1..L3 (full N, DOUT=512): agg chunk -> big gemm (128x256 tiles)
  auto run_layer = [&](const u16* hin, u16* hout, int din, int layer, bool relu) {
    for (int c0 = 0; c0 < N; c0 += chunk) {
      const int mc = imin_h(chunk, N - c0);
      const int ab = (mc + 3) / 4;
      if (din == IN_DIM)
        k_agg<IN_DIM, false><<<ab, 256, 0, stream>>>(hin, col, rowptr + c0, nullptr, CH, mc);
      else
        k_agg<HID, false><<<ab, 256, 0, stream>>>(hin, col, rowptr + c0, nullptr, CH, mc);
      const u16* a1 = hin + (size_t)c0 * din;
      u16* o = hout + (size_t)c0 * HID;
      const int mb = (mc + 127) / 128;
      if (din == IN_DIM && relu)
        k_gemm_big<IN_DIM, true><<<dim3(2, mb), 512, 0, stream>>>(
            a1, CH, WtS[layer], WtN[layer], Bias[layer], o, mc);
      else if (relu)
        k_gemm_big<HID, true><<<dim3(2, mb), 512, 0, stream>>>(
            a1, CH, WtS[layer], WtN[layer], Bias[layer], o, mc);
      else
        k_gemm_big<HID, false><<<dim3(2, mb), 512, 0, stream>>>(
            a1, CH, WtS[layer], WtN[layer], Bias[layer], o, mc);
    }
  };

  run_layer(HA, HB, IN_DIM, 0, true);   // L1: 128->512 relu   (HA h0 -> HB h1)
  run_layer(HB, HA, HID,    1, false);  // L2: 512->512        (HB h1 -> HA h2)
  run_layer(HA, HB, HID,    2, true);   // L3: 512->512 relu   (HA h2 -> HB h3)

  // L4 mask-restricted, loss fused into the GEMM epilogue (no decoded buffer)
  k_agg<HID, true><<<(NM + 3) / 4, 256, 0, stream>>>(HB, col, rowptr, mask, CH, NM);
  k_gemm_loss<HID, IN_DIM><<<dim3(1, (NM + 127) / 128), 256, 0, stream>>>(
      HB, CH, WtS[3], WtN[3], Bias[3], attr, partials, NM, mask);

  // loss = partials[0] / (NM*128)
  k_final<<<1, 1, 0, stream>>>(partials, (float*)d_out, 1.0f / ((float)NM * IN_DIM));
}

// Round 17
// 437.077 us; speedup vs baseline: 1.6181x; 1.0695x over previous
//
#include <hip/hip_runtime.h>
#include <cstdint>
#include <cstddef>

#define IN_DIM 128
#define HID    512

typedef unsigned int   uint32;
typedef unsigned short u16;
typedef __attribute__((ext_vector_type(8))) short bf16x8;   // 8 bf16 (4 VGPRs)
typedef __attribute__((ext_vector_type(4))) float f32x4;

static inline int imin_h(int a, int b) { return a < b ? a : b; }

// ---- bf16 helpers (storage-only bf16; accumulation fp32) ----
__device__ __forceinline__ float bfu2f(uint32 u) { return __uint_as_float(u << 16); }
__device__ __forceinline__ u16 f2bf(float f) {
  uint32 x = __float_as_uint(f);
  x += 0x7fffu + ((x >> 16) & 1u);           // round-to-nearest-even
  return (u16)(x >> 16);
}
__device__ __forceinline__ uint32 pack2(float a, float b) {
  return (uint32)f2bf(a) | ((uint32)f2bf(b) << 16);
}

#define GLOBAL_AS(p) ((const __attribute__((address_space(1))) void*)(p))
#define LDS_AS(p)    ((__attribute__((address_space(3))) void*)(p))

// ---------------- misc: zero two int arrays in one launch ----------------
__global__ void k_zero2(int* __restrict__ a, int na, int* __restrict__ b, int nb) {
  const int total = na + nb;
  for (int i = blockIdx.x * blockDim.x + threadIdx.x; i < total; i += gridDim.x * blockDim.x) {
    if (i < na) a[i] = 0;
    else        b[i - na] = 0;
  }
}

// ---------------- CSR build (by dst) ----------------
__global__ void k_hist(const int* __restrict__ dst, int* __restrict__ deg, int E) {
  for (int e = blockIdx.x * blockDim.x + threadIdx.x; e < E; e += gridDim.x * blockDim.x)
    atomicAdd(&deg[dst[e]], 1);
}

// ---- 3-phase multi-block exclusive scan (chunk = 2048 = 256 thr x 8) ----
__global__ __launch_bounds__(256)
void k_scan1(const int* __restrict__ deg, int* __restrict__ bsum, int n) {
  __shared__ int sm[256];
  const int base = blockIdx.x * 2048 + threadIdx.x * 8;
  int s = 0;
  if (base + 8 <= n) {
    const uint4 a = *reinterpret_cast<const uint4*>(deg + base);
    const uint4 b = *reinterpret_cast<const uint4*>(deg + base + 4);
    s = (int)(a.x + a.y + a.z + a.w + b.x + b.y + b.z + b.w);
  } else {
    for (int i = 0; i < 8; ++i) if (base + i < n) s += deg[base + i];
  }
  sm[threadIdx.x] = s;
  __syncthreads();
  for (int off = 128; off > 0; off >>= 1) {
    if (threadIdx.x < off) sm[threadIdx.x] += sm[threadIdx.x + off];
    __syncthreads();
  }
  if (threadIdx.x == 0) bsum[blockIdx.x] = sm[0];
}

__global__ __launch_bounds__(256)
void k_scan2(int* __restrict__ bsum, int nb, int* __restrict__ rowptr, int n) {
  __shared__ int sm[256];
  const int v = (threadIdx.x < nb) ? bsum[threadIdx.x] : 0;
  sm[threadIdx.x] = v;
  __syncthreads();
  for (int off = 1; off < 256; off <<= 1) {
    const int t = (threadIdx.x >= off) ? sm[threadIdx.x - off] : 0;
    __syncthreads();
    sm[threadIdx.x] += t;
    __syncthreads();
  }
  if (threadIdx.x < nb) bsum[threadIdx.x] = sm[threadIdx.x] - v;  // exclusive
  if (threadIdx.x == nb - 1) rowptr[n] = sm[threadIdx.x];          // total = E
}

__global__ __launch_bounds__(256)
void k_scan3(const int* __restrict__ deg, const int* __restrict__ bsum,
             int* __restrict__ rowptr, int* __restrict__ cursor, int n) {
  __shared__ int sm[256];
  const int base = blockIdx.x * 2048 + threadIdx.x * 8;
  int v[8];
  int s = 0;
#pragma unroll
  for (int i = 0; i < 8; ++i) {
    v[i] = (base + i < n) ? deg[base + i] : 0;
    s += v[i];
  }
  sm[threadIdx.x] = s;
  __syncthreads();
  for (int off = 1; off < 256; off <<= 1) {
    const int t = (threadIdx.x >= off) ? sm[threadIdx.x - off] : 0;
    __syncthreads();
    sm[threadIdx.x] += t;
    __syncthreads();
  }
  int run = bsum[blockIdx.x] + sm[threadIdx.x] - s;   // exclusive prefix for this thread
#pragma unroll
  for (int i = 0; i < 8; ++i) {
    if (base + i < n) { rowptr[base + i] = run; cursor[base + i] = run; }
    run += v[i];
  }
}

__global__ void k_fill(const int* __restrict__ src, const int* __restrict__ dst,
                       int* __restrict__ cursor, int* __restrict__ col, int E) {
  for (int e = blockIdx.x * blockDim.x + threadIdx.x; e < E; e += gridDim.x * blockDim.x) {
    const int p = atomicAdd(&cursor[dst[e]], 1);
    col[p] = src[e];
  }
}

// ---------------- h0 = bf16(attr); masked rows = token ----------------
__global__ void k_cvt(const float4* __restrict__ in, uint2* __restrict__ out, int n4) {
  for (int i = blockIdx.x * blockDim.x + threadIdx.x; i < n4; i += gridDim.x * blockDim.x) {
    const float4 v = in[i];
    out[i] = make_uint2(pack2(v.x, v.y), pack2(v.z, v.w));
  }
}

__global__ void k_mask(const float4* __restrict__ token, const int* __restrict__ mask,
                       uint2* __restrict__ h0, int NM) {
  const int total = NM * (IN_DIM / 4);
  for (int i = blockIdx.x * blockDim.x + threadIdx.x; i < total; i += gridDim.x * blockDim.x) {
    const int m = i >> 5;
    const int c = i & 31;
    const float4 t = token[c];
    h0[(size_t)mask[m] * (IN_DIM / 4) + c] = make_uint2(pack2(t.x, t.y), pack2(t.z, t.w));
  }
}

// ------- ALL weight transposes + convert + FRAGMENT-PACK in ONE launch ----------------
// frag f = (n>>4)*(K/32) + (k>>5); u16 idx = f*512 + ((k>>3)&3)*128 + (n&15)*8 + (k&7).
struct WtJobs {
  const float* W[8];
  u16* Wt[8];
  int K[8];
  int Nn[8];
  int start[9];     // cumulative element offsets; start[8] = total
};

__global__ __launch_bounds__(256)
void k_wt_all(WtJobs jobs) {
  const int total = jobs.start[8];
  for (int t = blockIdx.x * blockDim.x + threadIdx.x; t < total; t += gridDim.x * blockDim.x) {
    int s = 0;
#pragma unroll
    for (int i = 0; i < 7; ++i) s += (t >= jobs.start[i + 1]) ? 1 : 0;
    const int loc = t - jobs.start[s];
    const int K = jobs.K[s], Nn = jobs.Nn[s];
    const int n = loc / K, k = loc - n * K;
    const size_t idx = ((size_t)(n >> 4) * (K >> 5) + (k >> 5)) * 512 +
                       ((k >> 3) & 3) * 128 + ((n & 15) << 3) + (k & 7);
    jobs.Wt[s][idx] = f2bf(jobs.W[s][(size_t)k * Nn + n]);
  }
}

// -------- mean aggregation over in-neighbors (CSR gather, 1 wave/node, 4-deep MLP) ----
// 4-deep static-index ring (rule#20-safe); addition order preserved (e, e+1, e+2, e+3).
template <int D, bool REMAP>
__global__ __launch_bounds__(256)
void k_agg(const u16* __restrict__ h, const int* __restrict__ col,
           const int* __restrict__ rowptr, const int* __restrict__ nodes,
           u16* __restrict__ out, int n) {
  constexpr int V = D / 64;
  const int w = blockIdx.x * (blockDim.x >> 6) + (threadIdx.x >> 6);
  if (w >= n) return;
  const int node = REMAP ? nodes[w] : w;
  const int lane = threadIdx.x & 63;
  const int beg = rowptr[node], end = rowptr[node + 1];
  const size_t loff = (size_t)lane * V;
  float acc[V];
#pragma unroll
  for (int j = 0; j < V; ++j) acc[j] = 0.f;

  if constexpr (V == 8) {
    auto L = [&](int e) {
      return *reinterpret_cast<const uint4*>(h + (size_t)col[e] * D + loff);
    };
    uint4 b0{}, b1{}, b2{}, b3{};
    if (beg + 0 < end) b0 = L(beg + 0);
    if (beg + 1 < end) b1 = L(beg + 1);
    if (beg + 2 < end) b2 = L(beg + 2);
    if (beg + 3 < end) b3 = L(beg + 3);
    for (int e = beg; e < end; e += 4) {
      const uint4 c0 = b0, c1 = b1, c2 = b2, c3 = b3;
      if (e + 4 < end) b0 = L(e + 4);
      if (e + 5 < end) b1 = L(e + 5);
      if (e + 6 < end) b2 = L(e + 6);
      if (e + 7 < end) b3 = L(e + 7);
      // adds in original edge order
      acc[0] += bfu2f(c0.x & 0xffffu); acc[1] += bfu2f(c0.x >> 16);
      acc[2] += bfu2f(c0.y & 0xffffu); acc[3] += bfu2f(c0.y >> 16);
      acc[4] += bfu2f(c0.z & 0xffffu); acc[5] += bfu2f(c0.z >> 16);
      acc[6] += bfu2f(c0.w & 0xffffu); acc[7] += bfu2f(c0.w >> 16);
      if (e + 1 < end) {
        acc[0] += bfu2f(c1.x & 0xffffu); acc[1] += bfu2f(c1.x >> 16);
        acc[2] += bfu2f(c1.y & 0xffffu); acc[3] += bfu2f(c1.y >> 16);
        acc[4] += bfu2f(c1.z & 0xffffu); acc[5] += bfu2f(c1.z >> 16);
        acc[6] += bfu2f(c1.w & 0xffffu); acc[7] += bfu2f(c1.w >> 16);
      }
      if (e + 2 < end) {
        acc[0] += bfu2f(c2.x & 0xffffu); acc[1] += bfu2f(c2.x >> 16);
        acc[2] += bfu2f(c2.y & 0xffffu); acc[3] += bfu2f(c2.y >> 16);
        acc[4] += bfu2f(c2.z & 0xffffu); acc[5] += bfu2f(c2.z >> 16);
        acc[6] += bfu2f(c2.w & 0xffffu); acc[7] += bfu2f(c2.w >> 16);
      }
      if (e + 3 < end) {
        acc[0] += bfu2f(c3.x & 0xffffu); acc[1] += bfu2f(c3.x >> 16);
        acc[2] += bfu2f(c3.y & 0xffffu); acc[3] += bfu2f(c3.y >> 16);
        acc[4] += bfu2f(c3.z & 0xffffu); acc[5] += bfu2f(c3.z >> 16);
        acc[6] += bfu2f(c3.w & 0xffffu); acc[7] += bfu2f(c3.w >> 16);
      }
    }
  } else {
    auto L = [&](int e) {
      return *reinterpret_cast<const uint32*>(h + (size_t)col[e] * D + loff);
    };
    uint32 b0 = 0, b1 = 0, b2 = 0, b3 = 0;
    if (beg + 0 < end) b0 = L(beg + 0);
    if (beg + 1 < end) b1 = L(beg + 1);
    if (beg + 2 < end) b2 = L(beg + 2);
    if (beg + 3 < end) b3 = L(beg + 3);
    for (int e = beg; e < end; e += 4) {
      const uint32 c0 = b0, c1 = b1, c2 = b2, c3 = b3;
      if (e + 4 < end) b0 = L(e + 4);
      if (e + 5 < end) b1 = L(e + 5);
      if (e + 6 < end) b2 = L(e + 6);
      if (e + 7 < end) b3 = L(e + 7);
      acc[0] += bfu2f(c0 & 0xffffu); acc[1] += bfu2f(c0 >> 16);
      if (e + 1 < end) { acc[0] += bfu2f(c1 & 0xffffu); acc[1] += bfu2f(c1 >> 16); }
      if (e + 2 < end) { acc[0] += bfu2f(c2 & 0xffffu); acc[1] += bfu2f(c2 >> 16); }
      if (e + 3 < end) { acc[0] += bfu2f(c3 & 0xffffu); acc[1] += bfu2f(c3 >> 16); }
    }
  }

  const float inv = 1.0f / fmaxf((float)(end - beg), 1.0f);
  u16* o = out + (size_t)w * D + loff;
  if constexpr (V == 8) {
    uint4 u;
    u.x = pack2(acc[0] * inv, acc[1] * inv);
    u.y = pack2(acc[2] * inv, acc[3] * inv);
    u.z = pack2(acc[4] * inv, acc[5] * inv);
    u.w = pack2(acc[6] * inv, acc[7] * inv);
    *reinterpret_cast<uint4*>(o) = u;
  } else {
    *reinterpret_cast<uint32*>(o) = pack2(acc[0] * inv, acc[1] * inv);
  }
}

// ======== dual-A bf16 MFMA GEMM: 128x256 tile, 8 waves of 64x64 (R13-verified) =========
template <int DIN, bool RELU>
__global__ __launch_bounds__(512, 4)
void k_gemm_big(const u16* __restrict__ A1, const u16* __restrict__ A2,
                const u16* __restrict__ Wt1, const u16* __restrict__ Wt2,
                const float* __restrict__ bias, u16* __restrict__ out, int M) {
  constexpr int DOUT = HID;
  __shared__ char lds[73728];                 // 3 x (A 8KB + B 16KB); epilogue: 8 x 9216B
  constexpr int KS = DIN / 32;                // k-frags per phase
  constexpr int S  = 2 * KS;                  // total K-steps (dual-A)
  const int tid = threadIdx.x;
  const int w = tid >> 6, l = tid & 63;
  const int l15 = l & 15, l4 = l >> 4;
  const int wm = w >> 2, wn = w & 3;          // 2 x 4 wave grid, wave tile 64x64

  const int nwg  = gridDim.x * gridDim.y;
  const int orig = blockIdx.x + gridDim.x * blockIdx.y;
  const int q = nwg >> 3, r = nwg & 7;
  const int xcd = orig & 7, seq = orig >> 3;
  const int wg = (xcd < r ? xcd * (q + 1) : r * (q + 1) + (xcd - r) * q) + seq;
  const int mt = wg >> 1, nt = wg & 1;        // NT = 2
  const int m0 = mt * 128, n0 = nt * 256;

  f32x4 acc[4][4];
#pragma unroll
  for (int i = 0; i < 4; ++i)
#pragma unroll
    for (int j = 0; j < 4; ++j) acc[i][j] = (f32x4){0.f, 0.f, 0.f, 0.f};

  const int arow = min(m0 + w * 16 + l15, M - 1);
  const int kl = l4 * 8;
  const u16* pA1 = A1 + (size_t)arow * DIN + kl;
  const u16* pA2 = A2 + (size_t)arow * DIN + kl;
  const u16* bb1 = Wt1 + ((size_t)(n0 >> 4) + 2 * w) * KS * 512 + (size_t)l * 8;
  const u16* bb2 = Wt2 + ((size_t)(n0 >> 4) + 2 * w) * KS * 512 + (size_t)l * 8;

  auto stage = [&](int s) {                    // 3 global_load_lds per wave
    const int ph = s / KS;
    const int kf = s - ph * KS;
    char* buf = lds + (s % 3) * 24576;
    const u16* a0 = (ph ? pA2 : pA1) + kf * 32;
    const u16* b0 = (ph ? bb2 : bb1) + kf * 512;
    const u16* b1 = b0 + KS * 512;             // next n-frag
    __builtin_amdgcn_global_load_lds(GLOBAL_AS(a0), LDS_AS(buf + w * 1024), 16, 0, 0);
    __builtin_amdgcn_global_load_lds(GLOBAL_AS(b0), LDS_AS(buf + 8192 + (2 * w + 0) * 1024), 16, 0, 0);
    __builtin_amdgcn_global_load_lds(GLOBAL_AS(b1), LDS_AS(buf + 8192 + (2 * w + 1) * 1024), 16, 0, 0);
  };

  stage(0);
  stage(1);

#pragma unroll
  for (int s = 0; s < S; ++s) {
    if (s + 1 < S) asm volatile("s_waitcnt vmcnt(3)" ::: "memory");
    else           asm volatile("s_waitcnt vmcnt(0)" ::: "memory");
    __builtin_amdgcn_s_barrier();
    if (s + 2 < S) stage(s + 2);               // refills buf[(s-1)%3] — drained pre-barrier
    char* buf = lds + (s % 3) * 24576;
    bf16x8 af[4], bfr[4];
#pragma unroll
    for (int i = 0; i < 4; ++i)
      af[i] = *reinterpret_cast<const bf16x8*>(buf + (wm * 4 + i) * 1024 + l * 16);
#pragma unroll
    for (int j = 0; j < 4; ++j)
      bfr[j] = *reinterpret_cast<const bf16x8*>(buf + 8192 + (wn * 4 + j) * 1024 + l * 16);
#pragma unroll
    for (int i = 0; i < 4; ++i)
#pragma unroll
      for (int j = 0; j < 4; ++j)
        acc[i][j] = __builtin_amdgcn_mfma_f32_16x16x32_bf16(af[i], bfr[j], acc[i][j], 0, 0, 0);
    asm volatile("s_waitcnt lgkmcnt(0)" ::: "memory");   // reads of buf retired
  }
  __builtin_amdgcn_s_barrier();                // epilogue reuses pipeline LDS

  u16* eb = (u16*)(lds + w * 9216);
  float bv[4];
#pragma unroll
  for (int j = 0; j < 4; ++j) bv[j] = bias[n0 + wn * 64 + j * 16 + l15];
#pragma unroll
  for (int i = 0; i < 4; ++i)
#pragma unroll
    for (int j = 0; j < 4; ++j)
#pragma unroll
      for (int r = 0; r < 4; ++r) {
        const int lr = i * 16 + l4 * 4 + r;
        float t = acc[i][j][r] + bv[j];
        if (RELU) t = fmaxf(t, 0.f);
        eb[lr * 72 + j * 16 + l15] = f2bf(t);
      }
  asm volatile("s_waitcnt lgkmcnt(0)" ::: "memory");      // wave-local write->read order
#pragma unroll
  for (int p = 0; p < 8; ++p) {
    const int lr = p * 8 + (l >> 3);
    const int row = m0 + wm * 64 + lr;
    if (row < M) {
      const uint4 v = *reinterpret_cast<const uint4*>(eb + lr * 72 + (l & 7) * 8);
      *reinterpret_cast<uint4*>(out + (size_t)row * DOUT + n0 + wn * 64 + (l & 7) * 8) = v;
    }
  }
}

// -------- L4 fused: 128x128 4-wave GEMM (A1-row remap) + MSE loss accumulation ---------
template <int DIN, int DOUT>
__global__ __launch_bounds__(256, 3)
void k_gemm_loss(const u16* __restrict__ A1, const u16* __restrict__ A2,
                 const u16* __restrict__ Wt1, const u16* __restrict__ Wt2,
                 const float* __restrict__ bias, const float* __restrict__ attr,
                 float* __restrict__ partials, int M, const int* __restrict__ remap) {
  __shared__ char lds[49152];
  constexpr int KS = DIN / 32;
  constexpr int S  = 2 * KS;
  const int tid = threadIdx.x;
  const int w = tid >> 6, l = tid & 63;
  const int l15 = l & 15, l4 = l >> 4;
  const int wm = w >> 1, wn = w & 1;

  const int nwg  = gridDim.x * gridDim.y;
  const int orig = blockIdx.x + gridDim.x * blockIdx.y;
  const int q = nwg >> 3, r = nwg & 7;
  const int xcd = orig & 7, seq = orig >> 3;
  const int wg = (xcd < r ? xcd * (q + 1) : r * (q + 1) + (xcd - r) * q) + seq;
  constexpr int NT = DOUT / 128;
  const int mt = wg / NT, nt = wg - mt * NT;
  const int m0 = mt * 128, n0 = nt * 128;

  f32x4 acc[4][4];
#pragma unroll
  for (int i = 0; i < 4; ++i)
#pragma unroll
    for (int j = 0; j < 4; ++j) acc[i][j] = (f32x4){0.f, 0.f, 0.f, 0.f};

  const int am0 = min(m0 + (2 * w) * 16 + l15, M - 1);
  const int am1 = min(m0 + (2 * w + 1) * 16 + l15, M - 1);
  const int ar0 = remap[am0];
  const int ar1 = remap[am1];
  const int kl = l4 * 8;
  const u16* pA1r0 = A1 + (size_t)ar0 * DIN + kl;
  const u16* pA1r1 = A1 + (size_t)ar1 * DIN + kl;
  const u16* pA2r0 = A2 + (size_t)am0 * DIN + kl;
  const u16* pA2r1 = A2 + (size_t)am1 * DIN + kl;
  const u16* bb1 = Wt1 + ((size_t)(n0 >> 4) + 2 * w) * KS * 512 + (size_t)l * 8;
  const u16* bb2 = Wt2 + ((size_t)(n0 >> 4) + 2 * w) * KS * 512 + (size_t)l * 8;

  auto stage = [&](int s) {
    const int ph = s / KS;
    const int kf = s - ph * KS;
    char* buf = lds + (s % 3) * 16384;
    const u16* a0 = (ph ? pA2r0 : pA1r0) + kf * 32;
    const u16* a1 = (ph ? pA2r1 : pA1r1) + kf * 32;
    const u16* b0 = (ph ? bb2 : bb1) + kf * 512;
    const u16* b1 = b0 + KS * 512;
    __builtin_amdgcn_global_load_lds(GLOBAL_AS(a0), LDS_AS(buf + (2 * w + 0) * 1024), 16, 0, 0);
    __builtin_amdgcn_global_load_lds(GLOBAL_AS(a1), LDS_AS(buf + (2 * w + 1) * 1024), 16, 0, 0);
    __builtin_amdgcn_global_load_lds(GLOBAL_AS(b0), LDS_AS(buf + 8192 + (2 * w + 0) * 1024), 16, 0, 0);
    __builtin_amdgcn_global_load_lds(GLOBAL_AS(b1), LDS_AS(buf + 8192 + (2 * w + 1) * 1024), 16, 0, 0);
  };

  stage(0);
  stage(1);

#pragma unroll
  for (int s = 0; s < S; ++s) {
    if (s + 1 < S) asm volatile("s_waitcnt vmcnt(4)" ::: "memory");
    else           asm volatile("s_waitcnt vmcnt(0)" ::: "memory");
    __builtin_amdgcn_s_barrier();
    if (s + 2 < S) stage(s + 2);
    char* buf = lds + (s % 3) * 16384;
    bf16x8 af[4], bfr[4];
#pragma unroll
    for (int i = 0; i < 4; ++i)
      af[i] = *reinterpret_cast<const bf16x8*>(buf + (wm * 4 + i) * 1024 + l * 16);
#pragma unroll
    for (int j = 0; j < 4; ++j)
      bfr[j] = *reinterpret_cast<const bf16x8*>(buf + 8192 + (wn * 4 + j) * 1024 + l * 16);
#pragma unroll
    for (int i = 0; i < 4; ++i)
#pragma unroll
      for (int j = 0; j < 4; ++j)
        acc[i][j] = __builtin_amdgcn_mfma_f32_16x16x32_bf16(af[i], bfr[j], acc[i][j], 0, 0, 0);
    asm volatile("s_waitcnt lgkmcnt(0)" ::: "memory");
  }

  float lsum = 0.f;
#pragma unroll
  for (int j = 0; j < 4; ++j) {
    const int c = n0 + wn * 64 + j * 16 + l15;
    const float bv = bias[c];
#pragma unroll
    for (int i = 0; i < 4; ++i) {
      const int rowb = m0 + wm * 64 + i * 16 + l4 * 4;
#pragma unroll
      for (int r2 = 0; r2 < 4; ++r2) {
        const int row = rowb + r2;
        if (row < M) {
          const float t = bfu2f((uint32)f2bf(acc[i][j][r2] + bv));  // keep bf16 rounding
          const float d = t - attr[(size_t)remap[row] * IN_DIM + c];
          lsum += d * d;
        }
      }
    }
  }
  __syncthreads();
  float* sm = (float*)lds;
  sm[tid] = lsum;
  __syncthreads();
  for (int off2 = 128; off2 > 0; off2 >>= 1) {
    if (tid < off2) sm[tid] += sm[tid + off2];
    __syncthreads();
  }
  if (tid == 0) atomicAdd(&partials[0], sm[0]);
}

// ---------------- finalize: out = partials[0] / (NM*128) ----------------
__global__ void k_final(const float* __restrict__ partials, float* __restrict__ out, float inv) {
  out[0] = partials[0] * inv;
}

// ---------------- launch ----------------
extern "C" void kernel_launch(void* const* d_in, const int* in_sizes, int n_in,
                              void* d_out, int out_size, void* d_ws, size_t ws_size,
                              hipStream_t stream) {
  const float* attr  = (const float*)d_in[0];
  const float* token = (const float*)d_in[1];
  const int*   src   = (const int*)d_in[2];
  const int*   dst   = (const int*)d_in[3];
  const int*   mask  = (const int*)d_in[4];
  const float* Wself[4]  = {(const float*)d_in[5], (const float*)d_in[8],
                            (const float*)d_in[11], (const float*)d_in[14]};
  const float* Wneigh[4] = {(const float*)d_in[6], (const float*)d_in[9],
                            (const float*)d_in[12], (const float*)d_in[15]};
  const float* Bias[4]   = {(const float*)d_in[7], (const float*)d_in[10],
                            (const float*)d_in[13], (const float*)d_in[16]};
  const int N  = in_sizes[0] / IN_DIM;
  const int E  = in_sizes[2];
  const int NM = in_sizes[4];

  size_t off = 0;
  auto take = [&](size_t bytes) -> void* {
    void* p = (char*)d_ws + off;
    off += (bytes + 255) & ~(size_t)255;
    return p;
  };
  u16* HA = (u16*)take((size_t)N * HID * sizeof(u16));   // 51.2 MB
  u16* HB = (u16*)take((size_t)N * HID * sizeof(u16));   // 51.2 MB
  const int dims_in[4]  = {IN_DIM, HID, HID, HID};
  const int dims_out[4] = {HID, HID, HID, IN_DIM};
  u16* WtS[4]; u16* WtN[4];
  for (int i = 0; i < 4; ++i) {
    WtS[i] = (u16*)take((size_t)dims_in[i] * dims_out[i] * sizeof(u16));
    WtN[i] = (u16*)take((size_t)dims_in[i] * dims_out[i] * sizeof(u16));
  }
  int* deg    = (int*)take((size_t)N * sizeof(int));
  int* rowptr = (int*)take((size_t)(N + 1) * sizeof(int));
  int* cursor = (int*)take((size_t)N * sizeof(int));
  int* col    = (int*)take((size_t)E * sizeof(int));
  int* bsum   = (int*)take(256 * sizeof(int));
  float* partials = (float*)take(512 * sizeof(float));

  // agg chunk: one chunk covering N (rounded to 256)
  size_t rem = (ws_size > off + 4096) ? (ws_size - off - 4096) : 0;
  const int cap = (int)(rem / ((size_t)HID * sizeof(u16)));
  const int want = (N + 255) & ~255;
  int chunk = (cap >= want) ? want : (cap & ~255);
  if (chunk < 2048) chunk = 2048;
  u16* CH = (u16*)take((size_t)chunk * HID * sizeof(u16));

  // CSR build + zero loss accumulator (one launch)
  k_zero2<<<imin_h((N + 512 + 255) / 256, 1024), 256, 0, stream>>>(deg, N, (int*)partials, 512);
  const int eb = imin_h((E + 255) / 256, 4096);
  k_hist<<<eb, 256, 0, stream>>>(dst, deg, E);
  const int nb = (N + 2047) / 2048;
  k_scan1<<<nb, 256, 0, stream>>>(deg, bsum, N);
  k_scan2<<<1, 256, 0, stream>>>(bsum, nb, rowptr, N);
  k_scan3<<<nb, 256, 0, stream>>>(deg, bsum, rowptr, cursor, N);
  k_fill<<<eb, 256, 0, stream>>>(src, dst, cursor, col, E);

  // weights: all 8 transpose+pack jobs in ONE launch
  WtJobs jobs;
  int acc0 = 0;
  for (int i = 0; i < 4; ++i) {
    jobs.W[2 * i] = Wself[i];  jobs.Wt[2 * i] = WtS[i];
    jobs.K[2 * i] = dims_in[i]; jobs.Nn[2 * i] = dims_out[i];
    jobs.start[2 * i] = acc0;   acc0 += dims_in[i] * dims_out[i];
    jobs.W[2 * i + 1] = Wneigh[i]; jobs.Wt[2 * i + 1] = WtN[i];
    jobs.K[2 * i + 1] = dims_in[i]; jobs.Nn[2 * i + 1] = dims_out[i];
    jobs.start[2 * i + 1] = acc0;  acc0 += dims_in[i] * dims_out[i];
  }
  jobs.start[8] = acc0;
  k_wt_all<<<imin_h((acc0 + 255) / 256, 2048), 256, 0, stream>>>(jobs);

  // h0 = bf16(attr) with masked rows = token   (in HA as N x 128)
  const int n4 = N * (IN_DIM / 4);
  k_cvt<<<imin_h((n4 + 255) / 256, 2048), 256, 0, stream>>>((const float4*)attr, (uint2*)HA, n4);
  k_mask<<<imin_h((NM * (IN_DIM / 4) + 255) / 256, 2048), 256, 0, stream>>>(
      (const float4*)token, mask, (uint2*)HA, NM);

  // L1..L3 (full N, DOUT=512): agg chunk -> big gemm (128x256 tiles)
  auto run_layer = [&](const u16* hin, u16* hout, int din, int layer, bool relu) {
    for (int c0 = 0; c0 < N; c0 += chunk) {
      const int mc = imin_h(chunk, N - c0);
      const int ab = (mc + 3) / 4;
      if (din == IN_DIM)
        k_agg<IN_DIM, false><<<ab, 256, 0, stream>>>(hin, col, rowptr + c0, nullptr, CH, mc);
      else
        k_agg<HID, false><<<ab, 256, 0, stream>>>(hin, col, rowptr + c0, nullptr, CH, mc);
      const u16* a1 = hin + (size_t)c0 * din;
      u16* o = hout + (size_t)c0 * HID;
      const int mb = (mc + 127) / 128;
      if (din == IN_DIM && relu)
        k_gemm_big<IN_DIM, true><<<dim3(2, mb), 512, 0, stream>>>(
            a1, CH, WtS[layer], WtN[layer], Bias[layer], o, mc);
      else if (relu)
        k_gemm_big<HID, true><<<dim3(2, mb), 512, 0, stream>>>(
            a1, CH, WtS[layer], WtN[layer], Bias[layer], o, mc);
      else
        k_gemm_big<HID, false><<<dim3(2, mb), 512, 0, stream>>>(
            a1, CH, WtS[layer], WtN[layer], Bias[layer], o, mc);
    }
  };

  run_layer(HA, HB, IN_DIM, 0, true);   // L1: 128->512 relu   (HA h0 -> HB h1)
  run_layer(HB, HA, HID,    1, false);  // L2: 512->512        (HB h1 -> HA h2)
  run_layer(HA, HB, HID,    2, true);   // L3: 512->512 relu   (HA h2 -> HB h3)

  // L4 mask-restricted, loss fused into the GEMM epilogue (no decoded buffer)
  k_agg<HID, true><<<(NM + 3) / 4, 256, 0, stream>>>(HB, col, rowptr, mask, CH, NM);
  k_gemm_loss<HID, IN_DIM><<<dim3(1, (NM + 127) / 128), 256, 0, stream>>>(
      HB, CH, WtS[3], WtN[3], Bias[3], attr, partials, NM, mask);

  // loss = partials[0] / (NM*128)
  k_final<<<1, 1, 0, stream>>>(partials, (float*)d_out, 1.0f / ((float)NM * IN_DIM));
}

// Round 18
// 433.660 us; speedup vs baseline: 1.6308x; 1.0079x over previous
//
#include <hip/hip_runtime.h>
#include <cstdint>
#include <cstddef>

#define IN_DIM 128
#define HID    512

typedef unsigned int   uint32;
typedef unsigned short u16;
typedef __attribute__((ext_vector_type(8))) short bf16x8;   // 8 bf16 (4 VGPRs)
typedef __attribute__((ext_vector_type(4))) float f32x4;

static inline int imin_h(int a, int b) { return a < b ? a : b; }

// ---- bf16 helpers (storage-only bf16; accumulation fp32) ----
__device__ __forceinline__ float bfu2f(uint32 u) { return __uint_as_float(u << 16); }
__device__ __forceinline__ u16 f2bf(float f) {
  uint32 x = __float_as_uint(f);
  x += 0x7fffu + ((x >> 16) & 1u);           // round-to-nearest-even
  return (u16)(x >> 16);
}
__device__ __forceinline__ uint32 pack2(float a, float b) {
  return (uint32)f2bf(a) | ((uint32)f2bf(b) << 16);
}

#define GLOBAL_AS(p) ((const __attribute__((address_space(1))) void*)(p))
#define LDS_AS(p)    ((__attribute__((address_space(3))) void*)(p))

// ---------------- misc: zero two int arrays in one launch ----------------
__global__ void k_zero2(int* __restrict__ a, int na, int* __restrict__ b, int nb) {
  const int total = na + nb;
  for (int i = blockIdx.x * blockDim.x + threadIdx.x; i < total; i += gridDim.x * blockDim.x) {
    if (i < na) a[i] = 0;
    else        b[i - na] = 0;
  }
}

// ------- weight transpose jobs (fragment-pack layout) ---------------------------------
// frag f = (n>>4)*(K/32) + (k>>5); u16 idx = f*512 + ((k>>3)&3)*128 + (n&15)*8 + (k&7).
struct WtJobs {
  const float* W[8];
  u16* Wt[8];
  int K[8];
  int Nn[8];
  int start[9];     // cumulative element offsets; start[8] = total
};

// ---- fused prep #1: hist (atomics) + cvt attr->bf16 + all weight packs (independent) --
__global__ __launch_bounds__(256)
void k_prep1(const int* __restrict__ dst, int* __restrict__ deg, int E,
             const float4* __restrict__ attr4, uint2* __restrict__ h0, int n4,
             WtJobs jobs) {
  const int wtot = jobs.start[8];
  const int total = E + n4 + wtot;
  for (int i = blockIdx.x * blockDim.x + threadIdx.x; i < total; i += gridDim.x * blockDim.x) {
    if (i < E) {
      atomicAdd(&deg[dst[i]], 1);
    } else if (i < E + n4) {
      const int t = i - E;
      const float4 v = attr4[t];
      h0[t] = make_uint2(pack2(v.x, v.y), pack2(v.z, v.w));
    } else {
      const int t = i - E - n4;
      int s = 0;
#pragma unroll
      for (int j = 0; j < 7; ++j) s += (t >= jobs.start[j + 1]) ? 1 : 0;
      const int loc = t - jobs.start[s];
      const int K = jobs.K[s], Nn = jobs.Nn[s];
      const int n = loc / K, k = loc - n * K;
      const size_t idx = ((size_t)(n >> 4) * (K >> 5) + (k >> 5)) * 512 +
                         ((k >> 3) & 3) * 128 + ((n & 15) << 3) + (k & 7);
      jobs.Wt[s][idx] = f2bf(jobs.W[s][(size_t)k * Nn + n]);
    }
  }
}

// ---- 3-phase multi-block exclusive scan (chunk = 2048 = 256 thr x 8) ----
__global__ __launch_bounds__(256)
void k_scan1(const int* __restrict__ deg, int* __restrict__ bsum, int n) {
  __shared__ int sm[256];
  const int base = blockIdx.x * 2048 + threadIdx.x * 8;
  int s = 0;
  if (base + 8 <= n) {
    const uint4 a = *reinterpret_cast<const uint4*>(deg + base);
    const uint4 b = *reinterpret_cast<const uint4*>(deg + base + 4);
    s = (int)(a.x + a.y + a.z + a.w + b.x + b.y + b.z + b.w);
  } else {
    for (int i = 0; i < 8; ++i) if (base + i < n) s += deg[base + i];
  }
  sm[threadIdx.x] = s;
  __syncthreads();
  for (int off = 128; off > 0; off >>= 1) {
    if (threadIdx.x < off) sm[threadIdx.x] += sm[threadIdx.x + off];
    __syncthreads();
  }
  if (threadIdx.x == 0) bsum[blockIdx.x] = sm[0];
}

__global__ __launch_bounds__(256)
void k_scan2(int* __restrict__ bsum, int nb, int* __restrict__ rowptr, int n) {
  __shared__ int sm[256];
  const int v = (threadIdx.x < nb) ? bsum[threadIdx.x] : 0;
  sm[threadIdx.x] = v;
  __syncthreads();
  for (int off = 1; off < 256; off <<= 1) {
    const int t = (threadIdx.x >= off) ? sm[threadIdx.x - off] : 0;
    __syncthreads();
    sm[threadIdx.x] += t;
    __syncthreads();
  }
  if (threadIdx.x < nb) bsum[threadIdx.x] = sm[threadIdx.x] - v;  // exclusive
  if (threadIdx.x == nb - 1) rowptr[n] = sm[threadIdx.x];          // total = E
}

__global__ __launch_bounds__(256)
void k_scan3(const int* __restrict__ deg, const int* __restrict__ bsum,
             int* __restrict__ rowptr, int* __restrict__ cursor, int n) {
  __shared__ int sm[256];
  const int base = blockIdx.x * 2048 + threadIdx.x * 8;
  int v[8];
  int s = 0;
#pragma unroll
  for (int i = 0; i < 8; ++i) {
    v[i] = (base + i < n) ? deg[base + i] : 0;
    s += v[i];
  }
  sm[threadIdx.x] = s;
  __syncthreads();
  for (int off = 1; off < 256; off <<= 1) {
    const int t = (threadIdx.x >= off) ? sm[threadIdx.x - off] : 0;
    __syncthreads();
    sm[threadIdx.x] += t;
    __syncthreads();
  }
  int run = bsum[blockIdx.x] + sm[threadIdx.x] - s;   // exclusive prefix for this thread
#pragma unroll
  for (int i = 0; i < 8; ++i) {
    if (base + i < n) { rowptr[base + i] = run; cursor[base + i] = run; }
    run += v[i];
  }
}

// ---- fused prep #2: CSR fill (atomic cursor) + mask rows = token ----
__global__ void k_fillmask(const int* __restrict__ src, const int* __restrict__ dst,
                           int* __restrict__ cursor, int* __restrict__ col, int E,
                           const float4* __restrict__ token, const int* __restrict__ mask,
                           uint2* __restrict__ h0, int NM) {
  const int mtot = NM * (IN_DIM / 4);
  const int total = E + mtot;
  for (int i = blockIdx.x * blockDim.x + threadIdx.x; i < total; i += gridDim.x * blockDim.x) {
    if (i < E) {
      const int p = atomicAdd(&cursor[dst[i]], 1);
      col[p] = src[i];
    } else {
      const int t = i - E;
      const int m = t >> 5;
      const int c = t & 31;
      const float4 tv = token[c];
      h0[(size_t)mask[m] * (IN_DIM / 4) + c] = make_uint2(pack2(tv.x, tv.y), pack2(tv.z, tv.w));
    }
  }
}

// -------- mean aggregation over in-neighbors (CSR gather, 1 wave/node, 4-deep MLP) ----
template <int D, bool REMAP>
__global__ __launch_bounds__(256)
void k_agg(const u16* __restrict__ h, const int* __restrict__ col,
           const int* __restrict__ rowptr, const int* __restrict__ nodes,
           u16* __restrict__ out, int n) {
  constexpr int V = D / 64;
  const int w = blockIdx.x * (blockDim.x >> 6) + (threadIdx.x >> 6);
  if (w >= n) return;
  const int node = REMAP ? nodes[w] : w;
  const int lane = threadIdx.x & 63;
  const int beg = rowptr[node], end = rowptr[node + 1];
  const size_t loff = (size_t)lane * V;
  float acc[V];
#pragma unroll
  for (int j = 0; j < V; ++j) acc[j] = 0.f;

  if constexpr (V == 8) {
    auto L = [&](int e) {
      return *reinterpret_cast<const uint4*>(h + (size_t)col[e] * D + loff);
    };
    uint4 b0{}, b1{}, b2{}, b3{};
    if (beg + 0 < end) b0 = L(beg + 0);
    if (beg + 1 < end) b1 = L(beg + 1);
    if (beg + 2 < end) b2 = L(beg + 2);
    if (beg + 3 < end) b3 = L(beg + 3);
    for (int e = beg; e < end; e += 4) {
      const uint4 c0 = b0, c1 = b1, c2 = b2, c3 = b3;
      if (e + 4 < end) b0 = L(e + 4);
      if (e + 5 < end) b1 = L(e + 5);
      if (e + 6 < end) b2 = L(e + 6);
      if (e + 7 < end) b3 = L(e + 7);
      acc[0] += bfu2f(c0.x & 0xffffu); acc[1] += bfu2f(c0.x >> 16);
      acc[2] += bfu2f(c0.y & 0xffffu); acc[3] += bfu2f(c0.y >> 16);
      acc[4] += bfu2f(c0.z & 0xffffu); acc[5] += bfu2f(c0.z >> 16);
      acc[6] += bfu2f(c0.w & 0xffffu); acc[7] += bfu2f(c0.w >> 16);
      if (e + 1 < end) {
        acc[0] += bfu2f(c1.x & 0xffffu); acc[1] += bfu2f(c1.x >> 16);
        acc[2] += bfu2f(c1.y & 0xffffu); acc[3] += bfu2f(c1.y >> 16);
        acc[4] += bfu2f(c1.z & 0xffffu); acc[5] += bfu2f(c1.z >> 16);
        acc[6] += bfu2f(c1.w & 0xffffu); acc[7] += bfu2f(c1.w >> 16);
      }
      if (e + 2 < end) {
        acc[0] += bfu2f(c2.x & 0xffffu); acc[1] += bfu2f(c2.x >> 16);
        acc[2] += bfu2f(c2.y & 0xffffu); acc[3] += bfu2f(c2.y >> 16);
        acc[4] += bfu2f(c2.z & 0xffffu); acc[5] += bfu2f(c2.z >> 16);
        acc[6] += bfu2f(c2.w & 0xffffu); acc[7] += bfu2f(c2.w >> 16);
      }
      if (e + 3 < end) {
        acc[0] += bfu2f(c3.x & 0xffffu); acc[1] += bfu2f(c3.x >> 16);
        acc[2] += bfu2f(c3.y & 0xffffu); acc[3] += bfu2f(c3.y >> 16);
        acc[4] += bfu2f(c3.z & 0xffffu); acc[5] += bfu2f(c3.z >> 16);
        acc[6] += bfu2f(c3.w & 0xffffu); acc[7] += bfu2f(c3.w >> 16);
      }
    }
  } else {
    auto L = [&](int e) {
      return *reinterpret_cast<const uint32*>(h + (size_t)col[e] * D + loff);
    };
    uint32 b0 = 0, b1 = 0, b2 = 0, b3 = 0;
    if (beg + 0 < end) b0 = L(beg + 0);
    if (beg + 1 < end) b1 = L(beg + 1);
    if (beg + 2 < end) b2 = L(beg + 2);
    if (beg + 3 < end) b3 = L(beg + 3);
    for (int e = beg; e < end; e += 4) {
      const uint32 c0 = b0, c1 = b1, c2 = b2, c3 = b3;
      if (e + 4 < end) b0 = L(e + 4);
      if (e + 5 < end) b1 = L(e + 5);
      if (e + 6 < end) b2 = L(e + 6);
      if (e + 7 < end) b3 = L(e + 7);
      acc[0] += bfu2f(c0 & 0xffffu); acc[1] += bfu2f(c0 >> 16);
      if (e + 1 < end) { acc[0] += bfu2f(c1 & 0xffffu); acc[1] += bfu2f(c1 >> 16); }
      if (e + 2 < end) { acc[0] += bfu2f(c2 & 0xffffu); acc[1] += bfu2f(c2 >> 16); }
      if (e + 3 < end) { acc[0] += bfu2f(c3 & 0xffffu); acc[1] += bfu2f(c3 >> 16); }
    }
  }

  const float inv = 1.0f / fmaxf((float)(end - beg), 1.0f);
  u16* o = out + (size_t)w * D + loff;
  if constexpr (V == 8) {
    uint4 u;
    u.x = pack2(acc[0] * inv, acc[1] * inv);
    u.y = pack2(acc[2] * inv, acc[3] * inv);
    u.z = pack2(acc[4] * inv, acc[5] * inv);
    u.w = pack2(acc[6] * inv, acc[7] * inv);
    *reinterpret_cast<uint4*>(o) = u;
  } else {
    *reinterpret_cast<uint32*>(o) = pack2(acc[0] * inv, acc[1] * inv);
  }
}

// ======== dual-A bf16 MFMA GEMM: 128x256 tile, 4 waves of 64x128 (fat wave tile) =======
// LDS-read-BW was binding at 64x64 tiles (8 B/MFMA). 64x128 tile: acc[4][8] = 128 AGPR,
// LDS reads 48 KB/block-step (A 2x, B 2x) for 2x MFMA/wave -> 6 B/MFMA.
// ~208 regs/wave -> 2 waves/SIMD, 2 blocks/CU (LDS 72KB). Single-barrier 3-buf schedule,
// 6 loads/wave/step -> vmcnt(6/0). Epilogue rows 136 u16 (69.6 KB).
template <int DIN, bool RELU>
__global__ __launch_bounds__(256, 2)
void k_gemm_big(const u16* __restrict__ A1, const u16* __restrict__ A2,
                const u16* __restrict__ Wt1, const u16* __restrict__ Wt2,
                const float* __restrict__ bias, u16* __restrict__ out, int M) {
  constexpr int DOUT = HID;
  __shared__ char lds[73728];                 // 3 x (A 8KB + B 16KB); epilogue 4 x 17408B
  constexpr int KS = DIN / 32;                // k-frags per phase
  constexpr int S  = 2 * KS;                  // total K-steps (dual-A)
  const int tid = threadIdx.x;
  const int w = tid >> 6, l = tid & 63;       // 4 waves
  const int l15 = l & 15, l4 = l >> 4;
  const int wm = w >> 1, wn = w & 1;          // 2 x 2 wave grid, wave tile 64x128

  // bijective XCD swizzle (m204); n-tile fastest
  const int nwg  = gridDim.x * gridDim.y;
  const int orig = blockIdx.x + gridDim.x * blockIdx.y;
  const int q = nwg >> 3, r = nwg & 7;
  const int xcd = orig & 7, seq = orig >> 3;
  const int wg = (xcd < r ? xcd * (q + 1) : r * (q + 1) + (xcd - r) * q) + seq;
  const int mt = wg >> 1, nt = wg & 1;        // NT = 2
  const int m0 = mt * 128, n0 = nt * 256;

  f32x4 acc[4][8];
#pragma unroll
  for (int i = 0; i < 4; ++i)
#pragma unroll
    for (int j = 0; j < 8; ++j) acc[i][j] = (f32x4){0.f, 0.f, 0.f, 0.f};

  // staging: wave w stages A m-frags {2w,2w+1} and B n-frags {4w..4w+3} (6 loads/step)
  const int ar0 = min(m0 + (2 * w + 0) * 16 + l15, M - 1);
  const int ar1 = min(m0 + (2 * w + 1) * 16 + l15, M - 1);
  const int kl = l4 * 8;
  const u16* pA1r0 = A1 + (size_t)ar0 * DIN + kl;
  const u16* pA1r1 = A1 + (size_t)ar1 * DIN + kl;
  const u16* pA2r0 = A2 + (size_t)ar0 * DIN + kl;
  const u16* pA2r1 = A2 + (size_t)ar1 * DIN + kl;
  const u16* bb1 = Wt1 + ((size_t)(n0 >> 4) + 4 * w) * KS * 512 + (size_t)l * 8;
  const u16* bb2 = Wt2 + ((size_t)(n0 >> 4) + 4 * w) * KS * 512 + (size_t)l * 8;

  auto stage = [&](int s) {                    // 6 global_load_lds per wave
    const int ph = s / KS;
    const int kf = s - ph * KS;
    char* buf = lds + (s % 3) * 24576;
    const u16* a0 = (ph ? pA2r0 : pA1r0) + kf * 32;
    const u16* a1 = (ph ? pA2r1 : pA1r1) + kf * 32;
    const u16* b  = (ph ? bb2 : bb1) + kf * 512;
    __builtin_amdgcn_global_load_lds(GLOBAL_AS(a0), LDS_AS(buf + (2 * w + 0) * 1024), 16, 0, 0);
    __builtin_amdgcn_global_load_lds(GLOBAL_AS(a1), LDS_AS(buf + (2 * w + 1) * 1024), 16, 0, 0);
#pragma unroll
    for (int t = 0; t < 4; ++t)
      __builtin_amdgcn_global_load_lds(GLOBAL_AS(b + (size_t)t * KS * 512),
                                       LDS_AS(buf + 8192 + (4 * w + t) * 1024), 16, 0, 0);
  };

  stage(0);
  stage(1);

#pragma unroll
  for (int s = 0; s < S; ++s) {
    if (s + 1 < S) asm volatile("s_waitcnt vmcnt(6)" ::: "memory");
    else           asm volatile("s_waitcnt vmcnt(0)" ::: "memory");
    __builtin_amdgcn_s_barrier();
    if (s + 2 < S) stage(s + 2);               // refills buf[(s-1)%3] — drained pre-barrier
    char* buf = lds + (s % 3) * 24576;
    bf16x8 af[4], bfr[8];
#pragma unroll
    for (int i = 0; i < 4; ++i)
      af[i] = *reinterpret_cast<const bf16x8*>(buf + (wm * 4 + i) * 1024 + l * 16);
#pragma unroll
    for (int j = 0; j < 8; ++j)
      bfr[j] = *reinterpret_cast<const bf16x8*>(buf + 8192 + (wn * 8 + j) * 1024 + l * 16);
#pragma unroll
    for (int i = 0; i < 4; ++i)
#pragma unroll
      for (int j = 0; j < 8; ++j)
        acc[i][j] = __builtin_amdgcn_mfma_f32_16x16x32_bf16(af[i], bfr[j], acc[i][j], 0, 0, 0);
    asm volatile("s_waitcnt lgkmcnt(0)" ::: "memory");   // reads of buf retired
  }
  __builtin_amdgcn_s_barrier();                // epilogue reuses pipeline LDS

  // ---- coalesced epilogue: C/D (col=lane&15, row=(lane>>4)*4+reg) -> LDS -> global ----
  u16* eb = (u16*)(lds + w * 17408);           // 64 rows x 136 u16
  float bv[8];
#pragma unroll
  for (int j = 0; j < 8; ++j) bv[j] = bias[n0 + wn * 128 + j * 16 + l15];
#pragma unroll
  for (int i = 0; i < 4; ++i)
#pragma unroll
    for (int j = 0; j < 8; ++j)
#pragma unroll
      for (int r = 0; r < 4; ++r) {
        const int lr = i * 16 + l4 * 4 + r;
        float t = acc[i][j][r] + bv[j];
        if (RELU) t = fmaxf(t, 0.f);
        eb[lr * 136 + j * 16 + l15] = f2bf(t);
      }
  asm volatile("s_waitcnt lgkmcnt(0)" ::: "memory");      // wave-local write->read order
#pragma unroll
  for (int p = 0; p < 16; ++p) {
    const int lr = p * 4 + (l >> 4);
    const int row = m0 + wm * 64 + lr;
    if (row < M) {
      const uint4 v = *reinterpret_cast<const uint4*>(eb + lr * 136 + l15 * 8);
      *reinterpret_cast<uint4*>(out + (size_t)row * DOUT + n0 + wn * 128 + l15 * 8) = v;
    }
  }
}

// -------- L4 fused: 128x128 4-wave GEMM (A1-row remap) + MSE loss accumulation ---------
template <int DIN, int DOUT>
__global__ __launch_bounds__(256, 3)
void k_gemm_loss(const u16* __restrict__ A1, const u16* __restrict__ A2,
                 const u16* __restrict__ Wt1, const u16* __restrict__ Wt2,
                 const float* __restrict__ bias, const float* __restrict__ attr,
                 float* __restrict__ partials, int M, const int* __restrict__ remap) {
  __shared__ char lds[49152];
  constexpr int KS = DIN / 32;
  constexpr int S  = 2 * KS;
  const int tid = threadIdx.x;
  const int w = tid >> 6, l = tid & 63;
  const int l15 = l & 15, l4 = l >> 4;
  const int wm = w >> 1, wn = w & 1;

  const int nwg  = gridDim.x * gridDim.y;
  const int orig = blockIdx.x + gridDim.x * blockIdx.y;
  const int q = nwg >> 3, r = nwg & 7;
  const int xcd = orig & 7, seq = orig >> 3;
  const int wg = (xcd < r ? xcd * (q + 1) : r * (q + 1) + (xcd - r) * q) + seq;
  constexpr int NT = DOUT / 128;
  const int mt = wg / NT, nt = wg - mt * NT;
  const int m0 = mt * 128, n0 = nt * 128;

  f32x4 acc[4][4];
#pragma unroll
  for (int i = 0; i < 4; ++i)
#pragma unroll
    for (int j = 0; j < 4; ++j) acc[i][j] = (f32x4){0.f, 0.f, 0.f, 0.f};

  const int am0 = min(m0 + (2 * w) * 16 + l15, M - 1);
  const int am1 = min(m0 + (2 * w + 1) * 16 + l15, M - 1);
  const int ar0 = remap[am0];
  const int ar1 = remap[am1];
  const int kl = l4 * 8;
  const u16* pA1r0 = A1 + (size_t)ar0 * DIN + kl;
  const u16* pA1r1 = A1 + (size_t)ar1 * DIN + kl;
  const u16* pA2r0 = A2 + (size_t)am0 * DIN + kl;
  const u16* pA2r1 = A2 + (size_t)am1 * DIN + kl;
  const u16* bb1 = Wt1 + ((size_t)(n0 >> 4) + 2 * w) * KS * 512 + (size_t)l * 8;
  const u16* bb2 = Wt2 + ((size_t)(n0 >> 4) + 2 * w) * KS * 512 + (size_t)l * 8;

  auto stage = [&](int s) {
    const int ph = s / KS;
    const int kf = s - ph * KS;
    char* buf = lds + (s % 3) * 16384;
    const u16* a0 = (ph ? pA2r0 : pA1r0) + kf * 32;
    const u16* a1 = (ph ? pA2r1 : pA1r1) + kf * 32;
    const u16* b0 = (ph ? bb2 : bb1) + kf * 512;
    const u16* b1 = b0 + KS * 512;
    __builtin_amdgcn_global_load_lds(GLOBAL_AS(a0), LDS_AS(buf + (2 * w + 0) * 1024), 16, 0, 0);
    __builtin_amdgcn_global_load_lds(GLOBAL_AS(a1), LDS_AS(buf + (2 * w + 1) * 1024), 16, 0, 0);
    __builtin_amdgcn_global_load_lds(GLOBAL_AS(b0), LDS_AS(buf + 8192 + (2 * w + 0) * 1024), 16, 0, 0);
    __builtin_amdgcn_global_load_lds(GLOBAL_AS(b1), LDS_AS(buf + 8192 + (2 * w + 1) * 1024), 16, 0, 0);
  };

  stage(0);
  stage(1);

#pragma unroll
  for (int s = 0; s < S; ++s) {
    if (s + 1 < S) asm volatile("s_waitcnt vmcnt(4)" ::: "memory");
    else           asm volatile("s_waitcnt vmcnt(0)" ::: "memory");
    __builtin_amdgcn_s_barrier();
    if (s + 2 < S) stage(s + 2);
    char* buf = lds + (s % 3) * 16384;
    bf16x8 af[4], bfr[4];
#pragma unroll
    for (int i = 0; i < 4; ++i)
      af[i] = *reinterpret_cast<const bf16x8*>(buf + (wm * 4 + i) * 1024 + l * 16);
#pragma unroll
    for (int j = 0; j < 4; ++j)
      bfr[j] = *reinterpret_cast<const bf16x8*>(buf + 8192 + (wn * 4 + j) * 1024 + l * 16);
#pragma unroll
    for (int i = 0; i < 4; ++i)
#pragma unroll
      for (int j = 0; j < 4; ++j)
        acc[i][j] = __builtin_amdgcn_mfma_f32_16x16x32_bf16(af[i], bfr[j], acc[i][j], 0, 0, 0);
    asm volatile("s_waitcnt lgkmcnt(0)" ::: "memory");
  }

  float lsum = 0.f;
#pragma unroll
  for (int j = 0; j < 4; ++j) {
    const int c = n0 + wn * 64 + j * 16 + l15;
    const float bv = bias[c];
#pragma unroll
    for (int i = 0; i < 4; ++i) {
      const int rowb = m0 + wm * 64 + i * 16 + l4 * 4;
#pragma unroll
      for (int r2 = 0; r2 < 4; ++r2) {
        const int row = rowb + r2;
        if (row < M) {
          const float t = bfu2f((uint32)f2bf(acc[i][j][r2] + bv));  // keep bf16 rounding
          const float d = t - attr[(size_t)remap[row] * IN_DIM + c];
          lsum += d * d;
        }
      }
    }
  }
  __syncthreads();
  float* sm = (float*)lds;
  sm[tid] = lsum;
  __syncthreads();
  for (int off2 = 128; off2 > 0; off2 >>= 1) {
    if (tid < off2) sm[tid] += sm[tid + off2];
    __syncthreads();
  }
  if (tid == 0) atomicAdd(&partials[0], sm[0]);
}

// ---------------- finalize: out = partials[0] / (NM*128) ----------------
__global__ void k_final(const float* __restrict__ partials, float* __restrict__ out, float inv) {
  out[0] = partials[0] * inv;
}

// ---------------- launch ----------------
extern "C" void kernel_launch(void* const* d_in, const int* in_sizes, int n_in,
                              void* d_out, int out_size, void* d_ws, size_t ws_size,
                              hipStream_t stream) {
  const float* attr  = (const float*)d_in[0];
  const float* token = (const float*)d_in[1];
  const int*   src   = (const int*)d_in[2];
  const int*   dst   = (const int*)d_in[3];
  const int*   mask  = (const int*)d_in[4];
  const float* Wself[4]  = {(const float*)d_in[5], (const float*)d_in[8],
                            (const float*)d_in[11], (const float*)d_in[14]};
  const float* Wneigh[4] = {(const float*)d_in[6], (const float*)d_in[9],
                            (const float*)d_in[12], (const float*)d_in[15]};
  const float* Bias[4]   = {(const float*)d_in[7], (const float*)d_in[10],
                            (const float*)d_in[13], (const float*)d_in[16]};
  const int N  = in_sizes[0] / IN_DIM;
  const int E  = in_sizes[2];
  const int NM = in_sizes[4];

  size_t off = 0;
  auto take = [&](size_t bytes) -> void* {
    void* p = (char*)d_ws + off;
    off += (bytes + 255) & ~(size_t)255;
    return p;
  };
  u16* HA = (u16*)take((size_t)N * HID * sizeof(u16));   // 51.2 MB
  u16* HB = (u16*)take((size_t)N * HID * sizeof(u16));   // 51.2 MB
  const int dims_in[4]  = {IN_DIM, HID, HID, HID};
  const int dims_out[4] = {HID, HID, HID, IN_DIM};
  u16* WtS[4]; u16* WtN[4];
  for (int i = 0; i < 4; ++i) {
    WtS[i] = (u16*)take((size_t)dims_in[i] * dims_out[i] * sizeof(u16));
    WtN[i] = (u16*)take((size_t)dims_in[i] * dims_out[i] * sizeof(u16));
  }
  int* deg    = (int*)take((size_t)N * sizeof(int));
  int* rowptr = (int*)take((size_t)(N + 1) * sizeof(int));
  int* cursor = (int*)take((size_t)N * sizeof(int));
  int* col    = (int*)take((size_t)E * sizeof(int));
  int* bsum   = (int*)take(256 * sizeof(int));
  float* partials = (float*)take(512 * sizeof(float));

  // agg chunk: one chunk covering N (rounded to 256)
  size_t rem = (ws_size > off + 4096) ? (ws_size - off - 4096) : 0;
  const int cap = (int)(rem / ((size_t)HID * sizeof(u16)));
  const int want = (N + 255) & ~255;
  int chunk = (cap >= want) ? want : (cap & ~255);
  if (chunk < 2048) chunk = 2048;
  u16* CH = (u16*)take((size_t)chunk * HID * sizeof(u16));

  // zero deg + loss accumulator
  k_zero2<<<imin_h((N + 512 + 255) / 256, 1024), 256, 0, stream>>>(deg, N, (int*)partials, 512);

  // fused prep: hist + cvt + all weight packs
  WtJobs jobs;
  int acc0 = 0;
  for (int i = 0; i < 4; ++i) {
    jobs.W[2 * i] = Wself[i];  jobs.Wt[2 * i] = WtS[i];
    jobs.K[2 * i] = dims_in[i]; jobs.Nn[2 * i] = dims_out[i];
    jobs.start[2 * i] = acc0;   acc0 += dims_in[i] * dims_out[i];
    jobs.W[2 * i + 1] = Wneigh[i]; jobs.Wt[2 * i + 1] = WtN[i];
    jobs.K[2 * i + 1] = dims_in[i]; jobs.Nn[2 * i + 1] = dims_out[i];
    jobs.start[2 * i + 1] = acc0;  acc0 += dims_in[i] * dims_out[i];
  }
  jobs.start[8] = acc0;
  const int n4 = N * (IN_DIM / 4);
  const int p1 = E + n4 + acc0;
  k_prep1<<<imin_h((p1 + 255) / 256, 4096), 256, 0, stream>>>(
      dst, deg, E, (const float4*)attr, (uint2*)HA, n4, jobs);

  // scan chain
  const int nb = (N + 2047) / 2048;
  k_scan1<<<nb, 256, 0, stream>>>(deg, bsum, N);
  k_scan2<<<1, 256, 0, stream>>>(bsum, nb, rowptr, N);
  k_scan3<<<nb, 256, 0, stream>>>(deg, bsum, rowptr, cursor, N);

  // fused: CSR fill + mask token rows
  const int p2 = E + NM * (IN_DIM / 4);
  k_fillmask<<<imin_h((p2 + 255) / 256, 4096), 256, 0, stream>>>(
      src, dst, cursor, col, E, (const float4*)token, mask, (uint2*)HA, NM);

  // L1..L3 (full N, DOUT=512): agg chunk -> big gemm (128x256 tiles, 64x128 wave tiles)
  auto run_layer = [&](const u16* hin, u16* hout, int din, int layer, bool relu) {
    for (int c0 = 0; c0 < N; c0 += chunk) {
      const int mc = imin_h(chunk, N - c0);
      const int ab = (mc + 3) / 4;
      if (din == IN_DIM)
        k_agg<IN_DIM, false><<<ab, 256, 0, stream>>>(hin, col, rowptr + c0, nullptr, CH, mc);
      else
        k_agg<HID, false><<<ab, 256, 0, stream>>>(hin, col, rowptr + c0, nullptr, CH, mc);
      const u16* a1 = hin + (size_t)c0 * din;
      u16* o = hout + (size_t)c0 * HID;
      const int mb = (mc + 127) / 128;
      if (din == IN_DIM && relu)
        k_gemm_big<IN_DIM, true><<<dim3(2, mb), 256, 0, stream>>>(
            a1, CH, WtS[layer], WtN[layer], Bias[layer], o, mc);
      else if (relu)
        k_gemm_big<HID, true><<<dim3(2, mb), 256, 0, stream>>>(
            a1, CH, WtS[layer], WtN[layer], Bias[layer], o, mc);
      else
        k_gemm_big<HID, false><<<dim3(2, mb), 256, 0, stream>>>(
            a1, CH, WtS[layer], WtN[layer], Bias[layer], o, mc);
    }
  };

  run_layer(HA, HB, IN_DIM, 0, true);   // L1: 128->512 relu   (HA h0 -> HB h1)
  run_layer(HB, HA, HID,    1, false);  // L2: 512->512        (HB h1 -> HA h2)
  run_layer(HA, HB, HID,    2, true);   // L3: 512->512 relu   (HA h2 -> HB h3)

  // L4 mask-restricted, loss fused into the GEMM epilogue (no decoded buffer)
  k_agg<HID, true><<<(NM + 3) / 4, 256, 0, stream>>>(HB, col, rowptr, mask, CH, NM);
  k_gemm_loss<HID, IN_DIM><<<dim3(1, (NM + 127) / 128), 256, 0, stream>>>(
      HB, CH, WtS[3], WtN[3], Bias[3], attr, partials, NM, mask);

  // loss = partials[0] / (NM*128)
  k_final<<<1, 1, 0, stream>>>(partials, (float*)d_out, 1.0f / ((float)NM * IN_DIM));
}

// Round 19
// 431.386 us; speedup vs baseline: 1.6394x; 1.0053x over previous
//
#include <hip/hip_runtime.h>
#include <cstdint>
#include <cstddef>

#define IN_DIM 128
#define HID    512

typedef unsigned int   uint32;
typedef unsigned short u16;
typedef __attribute__((ext_vector_type(8))) short bf16x8;   // 8 bf16 (4 VGPRs)
typedef __attribute__((ext_vector_type(4))) float f32x4;

static inline int imin_h(int a, int b) { return a < b ? a : b; }

// ---- bf16 helpers (storage-only bf16; accumulation fp32) ----
__device__ __forceinline__ float bfu2f(uint32 u) { return __uint_as_float(u << 16); }
__device__ __forceinline__ u16 f2bf(float f) {
  uint32 x = __float_as_uint(f);
  x += 0x7fffu + ((x >> 16) & 1u);           // round-to-nearest-even
  return (u16)(x >> 16);
}
__device__ __forceinline__ uint32 pack2(float a, float b) {
  return (uint32)f2bf(a) | ((uint32)f2bf(b) << 16);
}

#define GLOBAL_AS(p) ((const __attribute__((address_space(1))) void*)(p))
#define LDS_AS(p)    ((__attribute__((address_space(3))) void*)(p))

// ---------------- misc: zero two int arrays in one launch ----------------
__global__ void k_zero2(int* __restrict__ a, int na, int* __restrict__ b, int nb) {
  const int total = na + nb;
  for (int i = blockIdx.x * blockDim.x + threadIdx.x; i < total; i += gridDim.x * blockDim.x) {
    if (i < na) a[i] = 0;
    else        b[i - na] = 0;
  }
}

// ------- weight transpose jobs (fragment-pack layout) ---------------------------------
// frag f = (n>>4)*(K/32) + (k>>5); u16 idx = f*512 + ((k>>3)&3)*128 + (n&15)*8 + (k&7).
struct WtJobs {
  const float* W[8];
  u16* Wt[8];
  int K[8];
  int Nn[8];
  int start[9];     // cumulative element offsets; start[8] = total
};

// ---- fused prep #1: hist (atomics) + cvt attr->bf16 + all weight packs (independent) --
__global__ __launch_bounds__(256)
void k_prep1(const int* __restrict__ dst, int* __restrict__ deg, int E,
             const float4* __restrict__ attr4, uint2* __restrict__ h0, int n4,
             WtJobs jobs) {
  const int wtot = jobs.start[8];
  const int total = E + n4 + wtot;
  for (int i = blockIdx.x * blockDim.x + threadIdx.x; i < total; i += gridDim.x * blockDim.x) {
    if (i < E) {
      atomicAdd(&deg[dst[i]], 1);
    } else if (i < E + n4) {
      const int t = i - E;
      const float4 v = attr4[t];
      h0[t] = make_uint2(pack2(v.x, v.y), pack2(v.z, v.w));
    } else {
      const int t = i - E - n4;
      int s = 0;
#pragma unroll
      for (int j = 0; j < 7; ++j) s += (t >= jobs.start[j + 1]) ? 1 : 0;
      const int loc = t - jobs.start[s];
      const int K = jobs.K[s], Nn = jobs.Nn[s];
      const int n = loc / K, k = loc - n * K;
      const size_t idx = ((size_t)(n >> 4) * (K >> 5) + (k >> 5)) * 512 +
                         ((k >> 3) & 3) * 128 + ((n & 15) << 3) + (k & 7);
      jobs.Wt[s][idx] = f2bf(jobs.W[s][(size_t)k * Nn + n]);
    }
  }
}

// ---- 3-phase multi-block exclusive scan (chunk = 2048 = 256 thr x 8) ----
__global__ __launch_bounds__(256)
void k_scan1(const int* __restrict__ deg, int* __restrict__ bsum, int n) {
  __shared__ int sm[256];
  const int base = blockIdx.x * 2048 + threadIdx.x * 8;
  int s = 0;
  if (base + 8 <= n) {
    const uint4 a = *reinterpret_cast<const uint4*>(deg + base);
    const uint4 b = *reinterpret_cast<const uint4*>(deg + base + 4);
    s = (int)(a.x + a.y + a.z + a.w + b.x + b.y + b.z + b.w);
  } else {
    for (int i = 0; i < 8; ++i) if (base + i < n) s += deg[base + i];
  }
  sm[threadIdx.x] = s;
  __syncthreads();
  for (int off = 128; off > 0; off >>= 1) {
    if (threadIdx.x < off) sm[threadIdx.x] += sm[threadIdx.x + off];
    __syncthreads();
  }
  if (threadIdx.x == 0) bsum[blockIdx.x] = sm[0];
}

__global__ __launch_bounds__(256)
void k_scan2(int* __restrict__ bsum, int nb, int* __restrict__ rowptr, int n) {
  __shared__ int sm[256];
  const int v = (threadIdx.x < nb) ? bsum[threadIdx.x] : 0;
  sm[threadIdx.x] = v;
  __syncthreads();
  for (int off = 1; off < 256; off <<= 1) {
    const int t = (threadIdx.x >= off) ? sm[threadIdx.x - off] : 0;
    __syncthreads();
    sm[threadIdx.x] += t;
    __syncthreads();
  }
  if (threadIdx.x < nb) bsum[threadIdx.x] = sm[threadIdx.x] - v;  // exclusive
  if (threadIdx.x == nb - 1) rowptr[n] = sm[threadIdx.x];          // total = E
}

__global__ __launch_bounds__(256)
void k_scan3(const int* __restrict__ deg, const int* __restrict__ bsum,
             int* __restrict__ rowptr, int* __restrict__ cursor, int n) {
  __shared__ int sm[256];
  const int base = blockIdx.x * 2048 + threadIdx.x * 8;
  int v[8];
  int s = 0;
#pragma unroll
  for (int i = 0; i < 8; ++i) {
    v[i] = (base + i < n) ? deg[base + i] : 0;
    s += v[i];
  }
  sm[threadIdx.x] = s;
  __syncthreads();
  for (int off = 1; off < 256; off <<= 1) {
    const int t = (threadIdx.x >= off) ? sm[threadIdx.x - off] : 0;
    __syncthreads();
    sm[threadIdx.x] += t;
    __syncthreads();
  }
  int run = bsum[blockIdx.x] + sm[threadIdx.x] - s;   // exclusive prefix for this thread
#pragma unroll
  for (int i = 0; i < 8; ++i) {
    if (base + i < n) { rowptr[base + i] = run; cursor[base + i] = run; }
    run += v[i];
  }
}

// ---- fused prep #2: CSR fill (atomic cursor) + mask rows = token ----
__global__ void k_fillmask(const int* __restrict__ src, const int* __restrict__ dst,
                           int* __restrict__ cursor, int* __restrict__ col, int E,
                           const float4* __restrict__ token, const int* __restrict__ mask,
                           uint2* __restrict__ h0, int NM) {
  const int mtot = NM * (IN_DIM / 4);
  const int total = E + mtot;
  for (int i = blockIdx.x * blockDim.x + threadIdx.x; i < total; i += gridDim.x * blockDim.x) {
    if (i < E) {
      const int p = atomicAdd(&cursor[dst[i]], 1);
      col[p] = src[i];
    } else {
      const int t = i - E;
      const int m = t >> 5;
      const int c = t & 31;
      const float4 tv = token[c];
      h0[(size_t)mask[m] * (IN_DIM / 4) + c] = make_uint2(pack2(tv.x, tv.y), pack2(tv.z, tv.w));
    }
  }
}

// -------- mean aggregation over in-neighbors (CSR gather, 1 wave/node, 8-wide burst) ---
// Chunk-of-8: all 8 independent row-loads issued before any add (8KB in flight/wave);
// zero-filled tails are exact identities (x+0.0f==x, acc never -0) => bitwise-identical.
template <int D, bool REMAP>
__global__ __launch_bounds__(256)
void k_agg(const u16* __restrict__ h, const int* __restrict__ col,
           const int* __restrict__ rowptr, const int* __restrict__ nodes,
           u16* __restrict__ out, int n) {
  constexpr int V = D / 64;
  const int w = blockIdx.x * (blockDim.x >> 6) + (threadIdx.x >> 6);
  if (w >= n) return;
  const int node = REMAP ? nodes[w] : w;
  const int lane = threadIdx.x & 63;
  const int beg = rowptr[node], end = rowptr[node + 1];
  const size_t loff = (size_t)lane * V;
  float acc[V];
#pragma unroll
  for (int j = 0; j < V; ++j) acc[j] = 0.f;

  if constexpr (V == 8) {
    auto L = [&](int e) {
      return *reinterpret_cast<const uint4*>(h + (size_t)col[e] * D + loff);
    };
    for (int e = beg; e < end; e += 8) {
      uint4 c0{}, c1{}, c2{}, c3{}, c4{}, c5{}, c6{}, c7{};
      c0 = L(e);
      if (e + 1 < end) c1 = L(e + 1);
      if (e + 2 < end) c2 = L(e + 2);
      if (e + 3 < end) c3 = L(e + 3);
      if (e + 4 < end) c4 = L(e + 4);
      if (e + 5 < end) c5 = L(e + 5);
      if (e + 6 < end) c6 = L(e + 6);
      if (e + 7 < end) c7 = L(e + 7);
#define ADD4(cv)                                                      \
      acc[0] += bfu2f(cv.x & 0xffffu); acc[1] += bfu2f(cv.x >> 16);   \
      acc[2] += bfu2f(cv.y & 0xffffu); acc[3] += bfu2f(cv.y >> 16);   \
      acc[4] += bfu2f(cv.z & 0xffffu); acc[5] += bfu2f(cv.z >> 16);   \
      acc[6] += bfu2f(cv.w & 0xffffu); acc[7] += bfu2f(cv.w >> 16);
      ADD4(c0) ADD4(c1) ADD4(c2) ADD4(c3) ADD4(c4) ADD4(c5) ADD4(c6) ADD4(c7)
#undef ADD4
    }
  } else {
    auto L = [&](int e) {
      return *reinterpret_cast<const uint32*>(h + (size_t)col[e] * D + loff);
    };
    for (int e = beg; e < end; e += 8) {
      uint32 c0 = 0, c1 = 0, c2 = 0, c3 = 0, c4 = 0, c5 = 0, c6 = 0, c7 = 0;
      c0 = L(e);
      if (e + 1 < end) c1 = L(e + 1);
      if (e + 2 < end) c2 = L(e + 2);
      if (e + 3 < end) c3 = L(e + 3);
      if (e + 4 < end) c4 = L(e + 4);
      if (e + 5 < end) c5 = L(e + 5);
      if (e + 6 < end) c6 = L(e + 6);
      if (e + 7 < end) c7 = L(e + 7);
#define ADD2(cv) acc[0] += bfu2f(cv & 0xffffu); acc[1] += bfu2f(cv >> 16);
      ADD2(c0) ADD2(c1) ADD2(c2) ADD2(c3) ADD2(c4) ADD2(c5) ADD2(c6) ADD2(c7)
#undef ADD2
    }
  }

  const float inv = 1.0f / fmaxf((float)(end - beg), 1.0f);
  u16* o = out + (size_t)w * D + loff;
  if constexpr (V == 8) {
    uint4 u;
    u.x = pack2(acc[0] * inv, acc[1] * inv);
    u.y = pack2(acc[2] * inv, acc[3] * inv);
    u.z = pack2(acc[4] * inv, acc[5] * inv);
    u.w = pack2(acc[6] * inv, acc[7] * inv);
    *reinterpret_cast<uint4*>(o) = u;
  } else {
    *reinterpret_cast<uint32*>(o) = pack2(acc[0] * inv, acc[1] * inv);
  }
}

// ======== dual-A bf16 MFMA GEMM: 128x256 tile, 8 waves of 64x64 (R13-verified) =========
// SINGLE-barrier K-loop: vmcnt(3) -> barrier -> stage(s+2) -> ds_read+MFMA -> lgkmcnt(0).
// 3 x 24KB rotating LDS; coalesced bf16 epilogue via LDS (72-u16 padded rows).
template <int DIN, bool RELU>
__global__ __launch_bounds__(512, 4)
void k_gemm_big(const u16* __restrict__ A1, const u16* __restrict__ A2,
                const u16* __restrict__ Wt1, const u16* __restrict__ Wt2,
                const float* __restrict__ bias, u16* __restrict__ out, int M) {
  constexpr int DOUT = HID;
  __shared__ char lds[73728];                 // 3 x (A 8KB + B 16KB); epilogue: 8 x 9216B
  constexpr int KS = DIN / 32;                // k-frags per phase
  constexpr int S  = 2 * KS;                  // total K-steps (dual-A)
  const int tid = threadIdx.x;
  const int w = tid >> 6, l = tid & 63;
  const int l15 = l & 15, l4 = l >> 4;
  const int wm = w >> 2, wn = w & 3;          // 2 x 4 wave grid, wave tile 64x64

  // bijective XCD swizzle (m204); n-tile fastest
  const int nwg  = gridDim.x * gridDim.y;
  const int orig = blockIdx.x + gridDim.x * blockIdx.y;
  const int q = nwg >> 3, r = nwg & 7;
  const int xcd = orig & 7, seq = orig >> 3;
  const int wg = (xcd < r ? xcd * (q + 1) : r * (q + 1) + (xcd - r) * q) + seq;
  const int mt = wg >> 1, nt = wg & 1;        // NT = 2
  const int m0 = mt * 128, n0 = nt * 256;

  f32x4 acc[4][4];
#pragma unroll
  for (int i = 0; i < 4; ++i)
#pragma unroll
    for (int j = 0; j < 4; ++j) acc[i][j] = (f32x4){0.f, 0.f, 0.f, 0.f};

  const int arow = min(m0 + w * 16 + l15, M - 1);
  const int kl = l4 * 8;
  const u16* pA1 = A1 + (size_t)arow * DIN + kl;
  const u16* pA2 = A2 + (size_t)arow * DIN + kl;
  const u16* bb1 = Wt1 + ((size_t)(n0 >> 4) + 2 * w) * KS * 512 + (size_t)l * 8;
  const u16* bb2 = Wt2 + ((size_t)(n0 >> 4) + 2 * w) * KS * 512 + (size_t)l * 8;

  auto stage = [&](int s) {                    // 3 global_load_lds per wave
    const int ph = s / KS;
    const int kf = s - ph * KS;
    char* buf = lds + (s % 3) * 24576;
    const u16* a0 = (ph ? pA2 : pA1) + kf * 32;
    const u16* b0 = (ph ? bb2 : bb1) + kf * 512;
    const u16* b1 = b0 + KS * 512;             // next n-frag
    __builtin_amdgcn_global_load_lds(GLOBAL_AS(a0), LDS_AS(buf + w * 1024), 16, 0, 0);
    __builtin_amdgcn_global_load_lds(GLOBAL_AS(b0), LDS_AS(buf + 8192 + (2 * w + 0) * 1024), 16, 0, 0);
    __builtin_amdgcn_global_load_lds(GLOBAL_AS(b1), LDS_AS(buf + 8192 + (2 * w + 1) * 1024), 16, 0, 0);
  };

  stage(0);
  stage(1);

#pragma unroll
  for (int s = 0; s < S; ++s) {
    if (s + 1 < S) asm volatile("s_waitcnt vmcnt(3)" ::: "memory");
    else           asm volatile("s_waitcnt vmcnt(0)" ::: "memory");
    __builtin_amdgcn_s_barrier();
    if (s + 2 < S) stage(s + 2);               // refills buf[(s-1)%3] — drained pre-barrier
    char* buf = lds + (s % 3) * 24576;
    bf16x8 af[4], bfr[4];
#pragma unroll
    for (int i = 0; i < 4; ++i)
      af[i] = *reinterpret_cast<const bf16x8*>(buf + (wm * 4 + i) * 1024 + l * 16);
#pragma unroll
    for (int j = 0; j < 4; ++j)
      bfr[j] = *reinterpret_cast<const bf16x8*>(buf + 8192 + (wn * 4 + j) * 1024 + l * 16);
#pragma unroll
    for (int i = 0; i < 4; ++i)
#pragma unroll
      for (int j = 0; j < 4; ++j)
        acc[i][j] = __builtin_amdgcn_mfma_f32_16x16x32_bf16(af[i], bfr[j], acc[i][j], 0, 0, 0);
    asm volatile("s_waitcnt lgkmcnt(0)" ::: "memory");   // reads of buf retired
  }
  __builtin_amdgcn_s_barrier();                // epilogue reuses pipeline LDS

  u16* eb = (u16*)(lds + w * 9216);
  float bv[4];
#pragma unroll
  for (int j = 0; j < 4; ++j) bv[j] = bias[n0 + wn * 64 + j * 16 + l15];
#pragma unroll
  for (int i = 0; i < 4; ++i)
#pragma unroll
    for (int j = 0; j < 4; ++j)
#pragma unroll
      for (int r = 0; r < 4; ++r) {
        const int lr = i * 16 + l4 * 4 + r;
        float t = acc[i][j][r] + bv[j];
        if (RELU) t = fmaxf(t, 0.f);
        eb[lr * 72 + j * 16 + l15] = f2bf(t);
      }
  asm volatile("s_waitcnt lgkmcnt(0)" ::: "memory");      // wave-local write->read order
#pragma unroll
  for (int p = 0; p < 8; ++p) {
    const int lr = p * 8 + (l >> 3);
    const int row = m0 + wm * 64 + lr;
    if (row < M) {
      const uint4 v = *reinterpret_cast<const uint4*>(eb + lr * 72 + (l & 7) * 8);
      *reinterpret_cast<uint4*>(out + (size_t)row * DOUT + n0 + wn * 64 + (l & 7) * 8) = v;
    }
  }
}

// -------- L4 fused: 128x128 4-wave GEMM (A1-row remap) + MSE loss accumulation ---------
template <int DIN, int DOUT>
__global__ __launch_bounds__(256, 3)
void k_gemm_loss(const u16* __restrict__ A1, const u16* __restrict__ A2,
                 const u16* __restrict__ Wt1, const u16* __restrict__ Wt2,
                 const float* __restrict__ bias, const float* __restrict__ attr,
                 float* __restrict__ partials, int M, const int* __restrict__ remap) {
  __shared__ char lds[49152];
  constexpr int KS = DIN / 32;
  constexpr int S  = 2 * KS;
  const int tid = threadIdx.x;
  const int w = tid >> 6, l = tid & 63;
  const int l15 = l & 15, l4 = l >> 4;
  const int wm = w >> 1, wn = w & 1;

  const int nwg  = gridDim.x * gridDim.y;
  const int orig = blockIdx.x + gridDim.x * blockIdx.y;
  const int q = nwg >> 3, r = nwg & 7;
  const int xcd = orig & 7, seq = orig >> 3;
  const int wg = (xcd < r ? xcd * (q + 1) : r * (q + 1) + (xcd - r) * q) + seq;
  constexpr int NT = DOUT / 128;
  const int mt = wg / NT, nt = wg - mt * NT;
  const int m0 = mt * 128, n0 = nt * 128;

  f32x4 acc[4][4];
#pragma unroll
  for (int i = 0; i < 4; ++i)
#pragma unroll
    for (int j = 0; j < 4; ++j) acc[i][j] = (f32x4){0.f, 0.f, 0.f, 0.f};

  const int am0 = min(m0 + (2 * w) * 16 + l15, M - 1);
  const int am1 = min(m0 + (2 * w + 1) * 16 + l15, M - 1);
  const int ar0 = remap[am0];
  const int ar1 = remap[am1];
  const int kl = l4 * 8;
  const u16* pA1r0 = A1 + (size_t)ar0 * DIN + kl;
  const u16* pA1r1 = A1 + (size_t)ar1 * DIN + kl;
  const u16* pA2r0 = A2 + (size_t)am0 * DIN + kl;
  const u16* pA2r1 = A2 + (size_t)am1 * DIN + kl;
  const u16* bb1 = Wt1 + ((size_t)(n0 >> 4) + 2 * w) * KS * 512 + (size_t)l * 8;
  const u16* bb2 = Wt2 + ((size_t)(n0 >> 4) + 2 * w) * KS * 512 + (size_t)l * 8;

  auto stage = [&](int s) {
    const int ph = s / KS;
    const int kf = s - ph * KS;
    char* buf = lds + (s % 3) * 16384;
    const u16* a0 = (ph ? pA2r0 : pA1r0) + kf * 32;
    const u16* a1 = (ph ? pA2r1 : pA1r1) + kf * 32;
    const u16* b0 = (ph ? bb2 : bb1) + kf * 512;
    const u16* b1 = b0 + KS * 512;
    __builtin_amdgcn_global_load_lds(GLOBAL_AS(a0), LDS_AS(buf + (2 * w + 0) * 1024), 16, 0, 0);
    __builtin_amdgcn_global_load_lds(GLOBAL_AS(a1), LDS_AS(buf + (2 * w + 1) * 1024), 16, 0, 0);
    __builtin_amdgcn_global_load_lds(GLOBAL_AS(b0), LDS_AS(buf + 8192 + (2 * w + 0) * 1024), 16, 0, 0);
    __builtin_amdgcn_global_load_lds(GLOBAL_AS(b1), LDS_AS(buf + 8192 + (2 * w + 1) * 1024), 16, 0, 0);
  };

  stage(0);
  stage(1);

#pragma unroll
  for (int s = 0; s < S; ++s) {
    if (s + 1 < S) asm volatile("s_waitcnt vmcnt(4)" ::: "memory");
    else           asm volatile("s_waitcnt vmcnt(0)" ::: "memory");
    __builtin_amdgcn_s_barrier();
    if (s + 2 < S) stage(s + 2);
    char* buf = lds + (s % 3) * 16384;
    bf16x8 af[4], bfr[4];
#pragma unroll
    for (int i = 0; i < 4; ++i)
      af[i] = *reinterpret_cast<const bf16x8*>(buf + (wm * 4 + i) * 1024 + l * 16);
#pragma unroll
    for (int j = 0; j < 4; ++j)
      bfr[j] = *reinterpret_cast<const bf16x8*>(buf + 8192 + (wn * 4 + j) * 1024 + l * 16);
#pragma unroll
    for (int i = 0; i < 4; ++i)
#pragma unroll
      for (int j = 0; j < 4; ++j)
        acc[i][j] = __builtin_amdgcn_mfma_f32_16x16x32_bf16(af[i], bfr[j], acc[i][j], 0, 0, 0);
    asm volatile("s_waitcnt lgkmcnt(0)" ::: "memory");
  }

  float lsum = 0.f;
#pragma unroll
  for (int j = 0; j < 4; ++j) {
    const int c = n0 + wn * 64 + j * 16 + l15;
    const float bv = bias[c];
#pragma unroll
    for (int i = 0; i < 4; ++i) {
      const int rowb = m0 + wm * 64 + i * 16 + l4 * 4;
#pragma unroll
      for (int r2 = 0; r2 < 4; ++r2) {
        const int row = rowb + r2;
        if (row < M) {
          const float t = bfu2f((uint32)f2bf(acc[i][j][r2] + bv));  // keep bf16 rounding
          const float d = t - attr[(size_t)remap[row] * IN_DIM + c];
          lsum += d * d;
        }
      }
    }
  }
  __syncthreads();
  float* sm = (float*)lds;
  sm[tid] = lsum;
  __syncthreads();
  for (int off2 = 128; off2 > 0; off2 >>= 1) {
    if (tid < off2) sm[tid] += sm[tid + off2];
    __syncthreads();
  }
  if (tid == 0) atomicAdd(&partials[0], sm[0]);
}

// ---------------- finalize: out = partials[0] / (NM*128) ----------------
__global__ void k_final(const float* __restrict__ partials, float* __restrict__ out, float inv) {
  out[0] = partials[0] * inv;
}

// ---------------- launch ----------------
extern "C" void kernel_launch(void* const* d_in, const int* in_sizes, int n_in,
                              void* d_out, int out_size, void* d_ws, size_t ws_size,
                              hipStream_t stream) {
  const float* attr  = (const float*)d_in[0];
  const float* token = (const float*)d_in[1];
  const int*   src   = (const int*)d_in[2];
  const int*   dst   = (const int*)d_in[3];
  const int*   mask  = (const int*)d_in[4];
  const float* Wself[4]  = {(const float*)d_in[5], (const float*)d_in[8],
                            (const float*)d_in[11], (const float*)d_in[14]};
  const float* Wneigh[4] = {(const float*)d_in[6], (const float*)d_in[9],
                            (const float*)d_in[12], (const float*)d_in[15]};
  const float* Bias[4]   = {(const float*)d_in[7], (const float*)d_in[10],
                            (const float*)d_in[13], (const float*)d_in[16]};
  const int N  = in_sizes[0] / IN_DIM;
  const int E  = in_sizes[2];
  const int NM = in_sizes[4];

  size_t off = 0;
  auto take = [&](size_t bytes) -> void* {
    void* p = (char*)d_ws + off;
    off += (bytes + 255) & ~(size_t)255;
    return p;
  };
  u16* HA = (u16*)take((size_t)N * HID * sizeof(u16));   // 51.2 MB
  u16* HB = (u16*)take((size_t)N * HID * sizeof(u16));   // 51.2 MB
  const int dims_in[4]  = {IN_DIM, HID, HID, HID};
  const int dims_out[4] = {HID, HID, HID, IN_DIM};
  u16* WtS[4]; u16* WtN[4];
  for (int i = 0; i < 4; ++i) {
    WtS[i] = (u16*)take((size_t)dims_in[i] * dims_out[i] * sizeof(u16));
    WtN[i] = (u16*)take((size_t)dims_in[i] * dims_out[i] * sizeof(u16));
  }
  int* deg    = (int*)take((size_t)N * sizeof(int));
  int* rowptr = (int*)take((size_t)(N + 1) * sizeof(int));
  int* cursor = (int*)take((size_t)N * sizeof(int));
  int* col    = (int*)take((size_t)E * sizeof(int));
  int* bsum   = (int*)take(256 * sizeof(int));
  float* partials = (float*)take(512 * sizeof(float));

  // agg chunk: one chunk covering N (rounded to 256)
  size_t rem = (ws_size > off + 4096) ? (ws_size - off - 4096) : 0;
  const int cap = (int)(rem / ((size_t)HID * sizeof(u16)));
  const int want = (N + 255) & ~255;
  int chunk = (cap >= want) ? want : (cap & ~255);
  if (chunk < 2048) chunk = 2048;
  u16* CH = (u16*)take((size_t)chunk * HID * sizeof(u16));

  // zero deg + loss accumulator
  k_zero2<<<imin_h((N + 512 + 255) / 256, 1024), 256, 0, stream>>>(deg, N, (int*)partials, 512);

  // fused prep: hist + cvt + all weight packs
  WtJobs jobs;
  int acc0 = 0;
  for (int i = 0; i < 4; ++i) {
    jobs.W[2 * i] = Wself[i];  jobs.Wt[2 * i] = WtS[i];
    jobs.K[2 * i] = dims_in[i]; jobs.Nn[2 * i] = dims_out[i];
    jobs.start[2 * i] = acc0;   acc0 += dims_in[i] * dims_out[i];
    jobs.W[2 * i + 1] = Wneigh[i]; jobs.Wt[2 * i + 1] = WtN[i];
    jobs.K[2 * i + 1] = dims_in[i]; jobs.Nn[2 * i + 1] = dims_out[i];
    jobs.start[2 * i + 1] = acc0;  acc0 += dims_in[i] * dims_out[i];
  }
  jobs.start[8] = acc0;
  const int n4 = N * (IN_DIM / 4);
  const int p1 = E + n4 + acc0;
  k_prep1<<<imin_h((p1 + 255) / 256, 4096), 256, 0, stream>>>(
      dst, deg, E, (const float4*)attr, (uint2*)HA, n4, jobs);

  // scan chain
  const int nb = (N + 2047) / 2048;
  k_scan1<<<nb, 256, 0, stream>>>(deg, bsum, N);
  k_scan2<<<1, 256, 0, stream>>>(bsum, nb, rowptr, N);
  k_scan3<<<nb, 256, 0, stream>>>(deg, bsum, rowptr, cursor, N);

  // fused: CSR fill + mask token rows
  const int p2 = E + NM * (IN_DIM / 4);
  k_fillmask<<<imin_h((p2 + 255) / 256, 4096), 256, 0, stream>>>(
      src, dst, cursor, col, E, (const float4*)token, mask, (uint2*)HA, NM);

  // L1..L3 (full N, DOUT=512): agg chunk -> big gemm (128x256 tiles)
  auto run_layer = [&](const u16* hin, u16* hout, int din, int layer, bool relu) {
    for (int c0 = 0; c0 < N; c0 += chunk) {
      const int mc = imin_h(chunk, N - c0);
      const int ab = (mc + 3) / 4;
      if (din == IN_DIM)
        k_agg<IN_DIM, false><<<ab, 256, 0, stream>>>(hin, col, rowptr + c0, nullptr, CH, mc);
      else
        k_agg<HID, false><<<ab, 256, 0, stream>>>(hin, col, rowptr + c0, nullptr, CH, mc);
      const u16* a1 = hin + (size_t)c0 * din;
      u16* o = hout + (size_t)c0 * HID;
      const int mb = (mc + 127) / 128;
      if (din == IN_DIM && relu)
        k_gemm_big<IN_DIM, true><<<dim3(2, mb), 512, 0, stream>>>(
            a1, CH, WtS[layer], WtN[layer], Bias[layer], o, mc);
      else if (relu)
        k_gemm_big<HID, true><<<dim3(2, mb), 512, 0, stream>>>(
            a1, CH, WtS[layer], WtN[layer], Bias[layer], o, mc);
      else
        k_gemm_big<HID, false><<<dim3(2, mb), 512, 0, stream>>>(
            a1, CH, WtS[layer], WtN[layer], Bias[layer], o, mc);
    }
  };

  run_layer(HA, HB, IN_DIM, 0, true);   // L1: 128->512 relu   (HA h0 -> HB h1)
  run_layer(HB, HA, HID,    1, false);  // L2: 512->512        (HB h1 -> HA h2)
  run_layer(HA, HB, HID,    2, true);   // L3: 512->512 relu   (HA h2 -> HB h3)

  // L4 mask-restricted, loss fused into the GEMM epilogue (no decoded buffer)
  k_agg<HID, true><<<(NM + 3) / 4, 256, 0, stream>>>(HB, col, rowptr, mask, CH, NM);
  k_gemm_loss<HID, IN_DIM><<<dim3(1, (NM + 127) / 128), 256, 0, stream>>>(
      HB, CH, WtS[3], WtN[3], Bias[3], attr, partials, NM, mask);

  // loss = partials[0] / (NM*128)
  k_final<<<1, 1, 0, stream>>>(partials, (float*)d_out, 1.0f / ((float)NM * IN_DIM));
}